// Round 1
// baseline (710.736 us; speedup 1.0000x reference)
//
#include <hip/hip_runtime.h>

#define N_PTS 4096
#define C_F   128
#define R_ROIS 128
#define G_    6
#define K_NB  16
#define M_GP  (R_ROIS * G_ * G_ * G_)   // 27648
#define COUT  64

// ---------------- workspace layout (bytes) ----------------
// gp:     27648*3*4      =   331,776
// pooled: 27648*64*4     = 7,077,888   (== flat, row-major (128, 13824))
// part:   4*128*1024*4   = 2,097,152   (split-K partials, reused per GEMM)
// t1:     128*1024*4     =   524,288
// sfc:    128*512*4      =   262,144
// h1:     128*1024*4     =   524,288
// h2:     128*512*4      =   262,144
// total ~= 11.08 MB
static constexpr size_t OFF_GP     = 0;
static constexpr size_t OFF_POOLED = 331776;
static constexpr size_t OFF_PART   = 7409664;
static constexpr size_t OFF_T1     = 9506816;
static constexpr size_t OFF_SFC    = 10031104;
static constexpr size_t OFF_H1     = 10293248;
static constexpr size_t OFF_H2     = 10817536;

// ---------------- grid points ----------------
__global__ __launch_bounds__(256) void grid_points_k(const float* __restrict__ rois,
                                                     float* __restrict__ gp) {
    int m = blockIdx.x * 256 + threadIdx.x;
    if (m >= M_GP) return;
    int r = m / 216, t = m % 216;
    int gi = t / 36, gj = (t / 6) % 6, gk = t % 6;
    const float* roi = rois + r * 7;
    float sx = roi[3], sy = roi[4], sz = roi[5];
    float lx = ((float)gi + 0.5f) / 6.0f * sx - sx * 0.5f;
    float ly = ((float)gj + 0.5f) / 6.0f * sy - sy * 0.5f;
    float lz = ((float)gk + 0.5f) / 6.0f * sz - sz * 0.5f;
    float c = cosf(roi[6]), s = sinf(roi[6]);
    gp[m * 3 + 0] = lx * c - ly * s + roi[0];
    gp[m * 3 + 1] = lx * s + ly * c + roi[1];
    gp[m * 3 + 2] = lz + roi[2];
}

// ---------------- search + point MLP + maxpool (one wave per grid point) ----
__global__ __launch_bounds__(64) void grid_pool_k(
    const float* __restrict__ xyz, const float* __restrict__ feats,
    const float* __restrict__ gp, const float* __restrict__ w1,
    const float* __restrict__ w2, float* __restrict__ pooled) {
    const float R2 = (float)(0.8 * 0.8);
    int m = blockIdx.x;
    int lane = threadIdx.x;
    __shared__ float s_g[K_NB][132];   // 131 used
    __shared__ float s_h1[K_NB][COUT];
    __shared__ int   s_idx[K_NB];

    float gx = gp[m * 3 + 0], gy = gp[m * 3 + 1], gz = gp[m * 3 + 2];

    // ---- select first <=16 in-radius point indices (ascending index order) ----
    int count = 0;
    for (int base = 0; base < N_PTS; base += 64) {
        int i = base + lane;
        float dx = xyz[i * 3 + 0] - gx;
        float dy = xyz[i * 3 + 1] - gy;
        float dz = xyz[i * 3 + 2] - gz;
        float d2 = dx * dx + dy * dy + dz * dz;
        bool in = d2 < R2;
        unsigned long long ball = __ballot(in);
        int before = __popcll(ball & ((1ull << lane) - 1ull));
        if (in) {
            int pos = count + before;
            if (pos < K_NB) s_idx[pos] = i;
        }
        count += __popcll(ball);
        if (count >= K_NB) break;
    }
    int c = min(count, K_NB);
    __syncthreads();

    // ---- build g = [rel(3) | feats(128)] rows for the c valid neighbors ----
    for (int t = lane; t < c * 131; t += 64) {
        int k = t / 131, j = t % 131;
        int pi = s_idx[k];
        float v;
        if (j < 3) {
            float gpj = (j == 0) ? gx : (j == 1) ? gy : gz;
            v = xyz[pi * 3 + j] - gpj;
        } else {
            v = feats[pi * 128 + (j - 3)];
        }
        s_g[k][j] = v;
    }
    __syncthreads();

    // ---- stage 1: h1 = relu(g @ w1), lane = output channel ----
    int cc = lane;
    float acc1[K_NB];
#pragma unroll
    for (int k = 0; k < K_NB; k++) acc1[k] = 0.f;
    for (int j = 0; j < 131; j++) {
        float wv = w1[j * 64 + cc];
#pragma unroll
        for (int k = 0; k < K_NB; k++) acc1[k] += s_g[k][j] * wv;
    }
#pragma unroll
    for (int k = 0; k < K_NB; k++) s_h1[k][cc] = fmaxf(acc1[k], 0.f);
    __syncthreads();

    // ---- stage 2: h2 = relu(h1 @ w2), maxpool over the c valid rows ----
    float acc2[K_NB];
#pragma unroll
    for (int k = 0; k < K_NB; k++) acc2[k] = 0.f;
    for (int j = 0; j < 64; j++) {
        float wv = w2[j * 64 + cc];
#pragma unroll
        for (int k = 0; k < K_NB; k++) acc2[k] += s_h1[k][j] * wv;
    }
    float best = 0.f;  // empty (c==0) -> 0, matching reference
    for (int k = 0; k < c; k++) best = fmaxf(best, fmaxf(acc2[k], 0.f));
    pooled[m * 64 + cc] = best;
}

// ---------------- split-K tiled fp32 GEMM: partials ----------------
// BM=32, BN=64, BK=32, 256 threads, 2x4 microtile. grid: (N/64, M/32, S)
__global__ __launch_bounds__(256) void gemm_part_k(
    const float* __restrict__ A, const float* __restrict__ B,
    float* __restrict__ P, int M, int N, int Kt, int S) {
    __shared__ float As[32][33];
    __shared__ float Bs[32][64];
    int tid = threadIdx.x;
    int s = blockIdx.z;
    int klen = Kt / S;
    int k0 = s * klen;
    int m0 = blockIdx.y * 32;
    int n0 = blockIdx.x * 64;
    int tx = tid % 16, ty = tid / 16;

    float acc[2][4];
#pragma unroll
    for (int i = 0; i < 2; i++)
#pragma unroll
        for (int j = 0; j < 4; j++) acc[i][j] = 0.f;

    for (int kt = 0; kt < klen; kt += 32) {
        {   // A tile 32m x 32k
            int mm = tid / 8;
            int kk = (tid % 8) * 4;
            const float* ap = A + (size_t)(m0 + mm) * Kt + k0 + kt + kk;
            float4 v = *(const float4*)ap;
            As[kk + 0][mm] = v.x; As[kk + 1][mm] = v.y;
            As[kk + 2][mm] = v.z; As[kk + 3][mm] = v.w;
        }
        {   // B tile 32k x 64n
            int kk = tid / 16;
            int nn = (tid % 16) * 4;
            const float4 v0 = *(const float4*)(B + (size_t)(k0 + kt + kk) * N + n0 + nn);
            *(float4*)&Bs[kk][nn] = v0;
            const float4 v1 = *(const float4*)(B + (size_t)(k0 + kt + kk + 16) * N + n0 + nn);
            *(float4*)&Bs[kk + 16][nn] = v1;
        }
        __syncthreads();
#pragma unroll
        for (int kk = 0; kk < 32; kk++) {
            float a0 = As[kk][ty * 2 + 0];
            float a1 = As[kk][ty * 2 + 1];
            float4 b = *(const float4*)&Bs[kk][tx * 4];
            acc[0][0] += a0 * b.x; acc[0][1] += a0 * b.y;
            acc[0][2] += a0 * b.z; acc[0][3] += a0 * b.w;
            acc[1][0] += a1 * b.x; acc[1][1] += a1 * b.y;
            acc[1][2] += a1 * b.z; acc[1][3] += a1 * b.w;
        }
        __syncthreads();
    }
#pragma unroll
    for (int i = 0; i < 2; i++) {
        int mrow = m0 + ty * 2 + i;
        float* pp = P + ((size_t)s * M + mrow) * N + n0 + tx * 4;
#pragma unroll
        for (int j = 0; j < 4; j++) pp[j] = acc[i][j];
    }
}

__global__ __launch_bounds__(256) void reduce_relu_k(const float* __restrict__ P,
                                                     float* __restrict__ C,
                                                     int MN, int S, int doRelu) {
    int i = blockIdx.x * 256 + threadIdx.x;
    if (i >= MN) return;
    float v = 0.f;
    for (int s = 0; s < S; s++) v += P[(size_t)s * MN + i];
    C[i] = doRelu ? fmaxf(v, 0.f) : v;
}

// ---------------- final head projection ----------------
__global__ __launch_bounds__(256) void head_out_k(const float* __restrict__ h2,
                                                  const float* __restrict__ w3,
                                                  const float* __restrict__ b3,
                                                  float* __restrict__ out, int P, int col0) {
    int t = blockIdx.x * 256 + threadIdx.x;
    if (t >= 128 * P) return;
    int r = t / P, p = t % P;
    float acc = b3[p];
    for (int j = 0; j < 512; j++) acc += h2[r * 512 + j] * w3[j * P + p];
    out[r * 9 + col0 + p] = acc;
}

static void launch_gemm(const float* A, const float* B, float* part, float* C,
                        int M, int N, int K, bool relu, hipStream_t stream) {
    const int S = 4;
    dim3 grid(N / 64, M / 32, S);
    hipLaunchKernelGGL(gemm_part_k, grid, dim3(256), 0, stream, A, B, part, M, N, K, S);
    int MN = M * N;
    hipLaunchKernelGGL(reduce_relu_k, dim3((MN + 255) / 256), dim3(256), 0, stream,
                       part, C, MN, S, relu ? 1 : 0);
}

extern "C" void kernel_launch(void* const* d_in, const int* in_sizes, int n_in,
                              void* d_out, int out_size, void* d_ws, size_t ws_size,
                              hipStream_t stream) {
    const float* xyz   = (const float*)d_in[0];
    const float* feats = (const float*)d_in[1];
    const float* rois  = (const float*)d_in[2];
    const float* w_m1  = (const float*)d_in[3];
    const float* w_m2  = (const float*)d_in[4];
    const float* w_s1  = (const float*)d_in[5];
    const float* w_s2  = (const float*)d_in[6];
    const float* w_c1  = (const float*)d_in[7];
    const float* w_c2  = (const float*)d_in[8];
    const float* w_c3  = (const float*)d_in[9];
    const float* b_c3  = (const float*)d_in[10];
    const float* w_i1  = (const float*)d_in[11];
    const float* w_i2  = (const float*)d_in[12];
    const float* w_i3  = (const float*)d_in[13];
    const float* b_i3  = (const float*)d_in[14];
    const float* w_r1  = (const float*)d_in[15];
    const float* w_r2  = (const float*)d_in[16];
    const float* w_r3  = (const float*)d_in[17];
    const float* b_r3  = (const float*)d_in[18];
    float* out = (float*)d_out;

    char* ws = (char*)d_ws;
    float* gp     = (float*)(ws + OFF_GP);
    float* pooled = (float*)(ws + OFF_POOLED);  // == flat (128 x 13824)
    float* part   = (float*)(ws + OFF_PART);
    float* t1     = (float*)(ws + OFF_T1);
    float* sfc    = (float*)(ws + OFF_SFC);
    float* h1     = (float*)(ws + OFF_H1);
    float* h2     = (float*)(ws + OFF_H2);

    hipLaunchKernelGGL(grid_points_k, dim3((M_GP + 255) / 256), dim3(256), 0, stream,
                       rois, gp);
    hipLaunchKernelGGL(grid_pool_k, dim3(M_GP), dim3(64), 0, stream,
                       xyz, feats, gp, w_m1, w_m2, pooled);

    // shared FC: flat(128x13824) @ w_s1(13824x1024) relu -> t1 ; t1 @ w_s2 relu -> sfc
    launch_gemm(pooled, w_s1, part, t1, 128, 1024, 13824, true, stream);
    launch_gemm(t1, w_s2, part, sfc, 128, 512, 1024, true, stream);

    // cls head
    launch_gemm(sfc, w_c1, part, h1, 128, 1024, 512, true, stream);
    launch_gemm(h1, w_c2, part, h2, 128, 512, 1024, true, stream);
    hipLaunchKernelGGL(head_out_k, dim3(1), dim3(256), 0, stream, h2, w_c3, b_c3, out, 1, 0);

    // iou head
    launch_gemm(sfc, w_i1, part, h1, 128, 1024, 512, true, stream);
    launch_gemm(h1, w_i2, part, h2, 128, 512, 1024, true, stream);
    hipLaunchKernelGGL(head_out_k, dim3(1), dim3(256), 0, stream, h2, w_i3, b_i3, out, 1, 1);

    // reg head
    launch_gemm(sfc, w_r1, part, h1, 128, 1024, 512, true, stream);
    launch_gemm(h1, w_r2, part, h2, 128, 512, 1024, true, stream);
    hipLaunchKernelGGL(head_out_k, dim3(4), dim3(256), 0, stream, h2, w_r3, b_r3, out, 7, 2);
}

// Round 3
// 565.563 us; speedup vs baseline: 1.2567x; 1.2567x over previous
//
#include <hip/hip_runtime.h>

typedef float  f32x4  __attribute__((ext_vector_type(4)));
typedef __bf16 bf16x8 __attribute__((ext_vector_type(8)));
typedef unsigned short ushort_t;

#define N_PTS 4096
#define R_ROIS 128
#define M_GP  27648
#define LDS_FENCE() asm volatile("s_waitcnt lgkmcnt(0)" ::: "memory")

// ---------------- workspace layout (bytes) ----------------
static constexpr size_t OFF_GP     = 0;          // 27648*3*4 = 331776
static constexpr size_t OFF_POOLED = 331776;     // 27648*64*4 = 7077888 (== flat 128x13824)
static constexpr size_t OFF_PART   = 7409664;    // 2 MB split-K partials; REUSED as cand list
static constexpr size_t OFF_T1     = 9506816;    // 512 KB t1; REUSED pool phase: ncand + weights
static constexpr size_t OFF_SFC    = 10031104;
static constexpr size_t OFF_H1     = 10293248;
static constexpr size_t OFF_H2     = 10817536;
// pool-phase sub-offsets inside T1 region:
static constexpr size_t OFF_NCAND  = OFF_T1;            // 128*4
static constexpr size_t OFF_W1TH   = OFF_T1 + 1024;     // 10752*2
static constexpr size_t OFF_W1TL   = OFF_T1 + 22528;    // 10752*2
static constexpr size_t OFF_W2TH   = OFF_T1 + 44032;    // 4608*2
static constexpr size_t OFF_W2TL   = OFF_T1 + 53248;    // 4608*2  (ends 62464 < 512KB)

static __device__ inline ushort_t f2bf(float f) {
    unsigned int u = __float_as_uint(f);
    unsigned int r = u + 0x7FFFu + ((u >> 16) & 1u);
    return (ushort_t)(r >> 16);
}
static __device__ inline float bf2f(ushort_t h) {
    return __uint_as_float(((unsigned int)h) << 16);
}

// ---------------- grid points ----------------
__global__ __launch_bounds__(256) void grid_points_k(const float* __restrict__ rois,
                                                     float* __restrict__ gp) {
    int m = blockIdx.x * 256 + threadIdx.x;
    if (m >= M_GP) return;
    int r = m / 216, t = m % 216;
    int gi = t / 36, gj = (t / 6) % 6, gk = t % 6;
    const float* roi = rois + r * 7;
    float sx = roi[3], sy = roi[4], sz = roi[5];
    float lx = ((float)gi + 0.5f) / 6.0f * sx - sx * 0.5f;
    float ly = ((float)gj + 0.5f) / 6.0f * sy - sy * 0.5f;
    float lz = ((float)gk + 0.5f) / 6.0f * sz - sz * 0.5f;
    float c = cosf(roi[6]), s = sinf(roi[6]);
    gp[m * 3 + 0] = lx * c - ly * s + roi[0];
    gp[m * 3 + 1] = lx * s + ly * c + roi[1];
    gp[m * 3 + 2] = lz + roi[2];
}

// ---------------- weight prep: transpose + pad + hi/lo bf16 split ------
__global__ __launch_bounds__(256) void prep_w_k(const float* __restrict__ w1,
                                                const float* __restrict__ w2,
                                                ushort_t* __restrict__ w1th,
                                                ushort_t* __restrict__ w1tl,
                                                ushort_t* __restrict__ w2th,
                                                ushort_t* __restrict__ w2tl) {
    int t = blockIdx.x * 256 + threadIdx.x;
    if (t < 10752) {
        int col = t / 168, k = t % 168;
        float v = (k < 131) ? w1[k * 64 + col] : 0.f;
        ushort_t hi = f2bf(v);
        w1th[t] = hi;
        w1tl[t] = f2bf(v - bf2f(hi));
    }
    if (t < 4608) {
        int col = t / 72, k = t % 72;
        float v = (k < 64) ? w2[k * 64 + col] : 0.f;
        ushort_t hi = f2bf(v);
        w2th[t] = hi;
        w2tl[t] = f2bf(v - bf2f(hi));
    }
}

// ---------------- per-RoI candidate lists (ascending index order) -------
__global__ __launch_bounds__(64) void roi_cand_k(const float* __restrict__ rois,
                                                 const float* __restrict__ xyz,
                                                 int* __restrict__ cand,
                                                 int* __restrict__ ncand) {
    int r = blockIdx.x;
    int lane = threadIdx.x;
    const float* roi = rois + r * 7;
    float cx = roi[0], cy = roi[1], cz = roi[2];
    float sx = roi[3], sy = roi[4], sz = roi[5];
    float Rc = 0.8f + 0.4166667f * sqrtf(sx * sx + sy * sy + sz * sz) + 0.01f;
    float Rc2 = Rc * Rc;
    int* cl = cand + r * N_PTS;
    int cnt = 0;
    for (int base = 0; base < N_PTS; base += 64) {
        int i = base + lane;
        float dx = xyz[i * 3 + 0] - cx;
        float dy = xyz[i * 3 + 1] - cy;
        float dz = xyz[i * 3 + 2] - cz;
        bool in = dx * dx + dy * dy + dz * dz < Rc2;
        unsigned long long ball = __ballot(in);
        int before = __popcll(ball & ((1ull << lane) - 1ull));
        if (in) cl[cnt + before] = i;
        cnt += __popcll(ball);
    }
    if (lane == 0) ncand[r] = cnt;
}

// ---------------- search + split-bf16 MFMA point-MLP + maxpool ----------
// one wave per block; 8 grid points per wave; grid = 27648/8 = 3456
__global__ __launch_bounds__(64) void grid_pool_mfma_k(
    const float* __restrict__ xyz, const float* __restrict__ feats,
    const float* __restrict__ gp, const int* __restrict__ cand,
    const int* __restrict__ ncand,
    const ushort_t* __restrict__ w1th, const ushort_t* __restrict__ w1tl,
    const ushort_t* __restrict__ w2th, const ushort_t* __restrict__ w2tl,
    float* __restrict__ pooled) {
    __shared__ __attribute__((aligned(16))) ushort_t s_gh[2688];  // [16][168]
    __shared__ __attribute__((aligned(16))) ushort_t s_gl[2688];
    __shared__ __attribute__((aligned(16))) ushort_t s_hh[1152];  // [16][72]
    __shared__ __attribute__((aligned(16))) ushort_t s_hl[1152];
    __shared__ int s_idx[16];

    int lane = threadIdx.x;
    const float R2 = (float)(0.8 * 0.8);
    int row = lane & 15, grp = lane >> 4;

    for (int it = 0; it < 8; it++) {
        int m = blockIdx.x * 8 + it;
        int r = m / 216;
        float gx = gp[m * 3 + 0], gy = gp[m * 3 + 1], gz = gp[m * 3 + 2];

        // ---- search first <=16 in-radius indices over RoI candidate list
        int nc = ncand[r];
        const int* cl = cand + (size_t)r * N_PTS;
        int count = 0;
        for (int base = 0; base < nc; base += 64) {
            int t = base + lane;
            bool in = false;
            int i = 0;
            if (t < nc) {
                i = cl[t];
                float dx = xyz[i * 3 + 0] - gx;
                float dy = xyz[i * 3 + 1] - gy;
                float dz = xyz[i * 3 + 2] - gz;
                in = dx * dx + dy * dy + dz * dz < R2;
            }
            unsigned long long ball = __ballot(in);
            int before = __popcll(ball & ((1ull << lane) - 1ull));
            int pos = count + before;
            if (in && pos < 16) s_idx[pos] = i;
            count += __popcll(ball);
            if (count >= 16) break;
        }
        int c = min(count, 16);
        LDS_FENCE();

        if (c == 0) {
            pooled[(size_t)m * 64 + lane] = 0.f;
            continue;
        }
        if (lane == 0) {                 // pad with first valid index
            int f = s_idx[0];
            for (int p = c; p < 16; p++) s_idx[p] = f;
        }
        LDS_FENCE();

        // ---- gather g = [rel(3) | feats(128)] -> hi/lo bf16 LDS (pad to 168)
        float gsel = (lane == 0) ? gx : (lane == 1) ? gy : gz;
        for (int k = 0; k < 16; k++) {
            int pi = s_idx[k];
            const float* fp = feats + (size_t)pi * 128;
            float v0 = (lane < 3) ? (xyz[pi * 3 + lane] - gsel) : fp[lane - 3];
            ushort_t h0 = f2bf(v0);
            s_gh[k * 168 + lane] = h0;
            s_gl[k * 168 + lane] = f2bf(v0 - bf2f(h0));
            float v1 = fp[61 + lane];
            ushort_t h1v = f2bf(v1);
            s_gh[k * 168 + 64 + lane] = h1v;
            s_gl[k * 168 + 64 + lane] = f2bf(v1 - bf2f(h1v));
            if (lane < 40) {             // channels 128..130, zero-pad 131..167
                float v2 = (lane < 3) ? fp[125 + lane] : 0.f;
                ushort_t h2v = f2bf(v2);
                s_gh[k * 168 + 128 + lane] = h2v;
                s_gl[k * 168 + 128 + lane] = f2bf(v2 - bf2f(h2v));
            }
        }
        LDS_FENCE();

        // ---- stage 1: (16x168) @ (168x64), 5 k-steps x 4 n-tiles x 3 terms
        f32x4 a0 = {0.f, 0.f, 0.f, 0.f}, a1 = a0, a2 = a0, a3 = a0;
#pragma unroll
        for (int ks = 0; ks < 5; ks++) {
            int ao = row * 168 + ks * 32 + grp * 8;
            bf16x8 ah = *(const bf16x8*)&s_gh[ao];
            bf16x8 al = *(const bf16x8*)&s_gl[ao];
#pragma unroll
            for (int nt = 0; nt < 4; nt++) {
                int bo = (nt * 16 + row) * 168 + ks * 32 + grp * 8;
                bf16x8 bh = *(const bf16x8*)&w1th[bo];
                bf16x8 bl = *(const bf16x8*)&w1tl[bo];
                f32x4 acc = (nt == 0) ? a0 : (nt == 1) ? a1 : (nt == 2) ? a2 : a3;
                acc = __builtin_amdgcn_mfma_f32_16x16x32_bf16(ah, bh, acc, 0, 0, 0);
                acc = __builtin_amdgcn_mfma_f32_16x16x32_bf16(al, bh, acc, 0, 0, 0);
                acc = __builtin_amdgcn_mfma_f32_16x16x32_bf16(ah, bl, acc, 0, 0, 0);
                if (nt == 0) a0 = acc; else if (nt == 1) a1 = acc;
                else if (nt == 2) a2 = acc; else a3 = acc;
            }
        }
        // relu -> h1 hi/lo bf16 LDS: D row=(grp*4+reg), col=(nt*16+row)
#pragma unroll
        for (int reg = 0; reg < 4; reg++) {
            int hrow = grp * 4 + reg;
#pragma unroll
            for (int nt = 0; nt < 4; nt++) {
                f32x4 pv = (nt == 0) ? a0 : (nt == 1) ? a1 : (nt == 2) ? a2 : a3;
                float v = fmaxf(pv[reg], 0.f);
                ushort_t hh = f2bf(v);
                s_hh[hrow * 72 + nt * 16 + row] = hh;
                s_hl[hrow * 72 + nt * 16 + row] = f2bf(v - bf2f(hh));
            }
        }
        LDS_FENCE();

        // ---- stage 2: (16x64) @ (64x64), 2 k-steps x 4 n-tiles x 3 terms
        f32x4 p0 = {0.f, 0.f, 0.f, 0.f}, p1 = p0, p2 = p0, p3 = p0;
#pragma unroll
        for (int ks = 0; ks < 2; ks++) {
            int ao = row * 72 + ks * 32 + grp * 8;
            bf16x8 ah = *(const bf16x8*)&s_hh[ao];
            bf16x8 al = *(const bf16x8*)&s_hl[ao];
#pragma unroll
            for (int nt = 0; nt < 4; nt++) {
                int bo = (nt * 16 + row) * 72 + ks * 32 + grp * 8;
                bf16x8 bh = *(const bf16x8*)&w2th[bo];
                bf16x8 bl = *(const bf16x8*)&w2tl[bo];
                f32x4 acc = (nt == 0) ? p0 : (nt == 1) ? p1 : (nt == 2) ? p2 : p3;
                acc = __builtin_amdgcn_mfma_f32_16x16x32_bf16(ah, bh, acc, 0, 0, 0);
                acc = __builtin_amdgcn_mfma_f32_16x16x32_bf16(al, bh, acc, 0, 0, 0);
                acc = __builtin_amdgcn_mfma_f32_16x16x32_bf16(ah, bl, acc, 0, 0, 0);
                if (nt == 0) p0 = acc; else if (nt == 1) p1 = acc;
                else if (nt == 2) p2 = acc; else p3 = acc;
            }
        }
        // ---- relu + max over 16 rows (padded rows duplicate row0) ----
#pragma unroll
        for (int nt = 0; nt < 4; nt++) {
            f32x4 pv = (nt == 0) ? p0 : (nt == 1) ? p1 : (nt == 2) ? p2 : p3;
            float mv = fmaxf(fmaxf(fmaxf(pv[0], pv[1]), fmaxf(pv[2], pv[3])), 0.f);
            mv = fmaxf(mv, __shfl_xor(mv, 16));
            mv = fmaxf(mv, __shfl_xor(mv, 32));
            if (grp == 0) pooled[(size_t)m * 64 + nt * 16 + row] = mv;
        }
    }
}

// ---------------- split-K tiled fp32 GEMM: partials ----------------
__global__ __launch_bounds__(256) void gemm_part_k(
    const float* __restrict__ A, const float* __restrict__ B,
    float* __restrict__ P, int M, int N, int Kt, int S) {
    __shared__ float As[32][33];
    __shared__ float Bs[32][64];
    int tid = threadIdx.x;
    int s = blockIdx.z;
    int klen = Kt / S;
    int k0 = s * klen;
    int m0 = blockIdx.y * 32;
    int n0 = blockIdx.x * 64;
    int tx = tid % 16, ty = tid / 16;

    float acc[2][4];
#pragma unroll
    for (int i = 0; i < 2; i++)
#pragma unroll
        for (int j = 0; j < 4; j++) acc[i][j] = 0.f;

    for (int kt = 0; kt < klen; kt += 32) {
        {
            int mm = tid / 8;
            int kk = (tid % 8) * 4;
            const float* ap = A + (size_t)(m0 + mm) * Kt + k0 + kt + kk;
            float4 v = *(const float4*)ap;
            As[kk + 0][mm] = v.x; As[kk + 1][mm] = v.y;
            As[kk + 2][mm] = v.z; As[kk + 3][mm] = v.w;
        }
        {
            int kk = tid / 16;
            int nn = (tid % 16) * 4;
            const float4 v0 = *(const float4*)(B + (size_t)(k0 + kt + kk) * N + n0 + nn);
            *(float4*)&Bs[kk][nn] = v0;
            const float4 v1 = *(const float4*)(B + (size_t)(k0 + kt + kk + 16) * N + n0 + nn);
            *(float4*)&Bs[kk + 16][nn] = v1;
        }
        __syncthreads();
#pragma unroll
        for (int kk = 0; kk < 32; kk++) {
            float a0 = As[kk][ty * 2 + 0];
            float a1 = As[kk][ty * 2 + 1];
            float4 b = *(const float4*)&Bs[kk][tx * 4];
            acc[0][0] += a0 * b.x; acc[0][1] += a0 * b.y;
            acc[0][2] += a0 * b.z; acc[0][3] += a0 * b.w;
            acc[1][0] += a1 * b.x; acc[1][1] += a1 * b.y;
            acc[1][2] += a1 * b.z; acc[1][3] += a1 * b.w;
        }
        __syncthreads();
    }
#pragma unroll
    for (int i = 0; i < 2; i++) {
        int mrow = m0 + ty * 2 + i;
        float* pp = P + ((size_t)s * M + mrow) * N + n0 + tx * 4;
#pragma unroll
        for (int j = 0; j < 4; j++) pp[j] = acc[i][j];
    }
}

__global__ __launch_bounds__(256) void reduce_relu_k(const float* __restrict__ P,
                                                     float* __restrict__ C,
                                                     int MN, int S, int doRelu) {
    int i = blockIdx.x * 256 + threadIdx.x;
    if (i >= MN) return;
    float v = 0.f;
    for (int s = 0; s < S; s++) v += P[(size_t)s * MN + i];
    C[i] = doRelu ? fmaxf(v, 0.f) : v;
}

// ---------------- final head projection ----------------
__global__ __launch_bounds__(256) void head_out_k(const float* __restrict__ h2,
                                                  const float* __restrict__ w3,
                                                  const float* __restrict__ b3,
                                                  float* __restrict__ out, int P, int col0) {
    int t = blockIdx.x * 256 + threadIdx.x;
    if (t >= 128 * P) return;
    int r = t / P, p = t % P;
    float acc = b3[p];
    for (int j = 0; j < 512; j++) acc += h2[r * 512 + j] * w3[j * P + p];
    out[r * 9 + col0 + p] = acc;
}

static void launch_gemm(const float* A, const float* B, float* part, float* C,
                        int M, int N, int K, bool relu, hipStream_t stream) {
    const int S = 4;
    dim3 grid(N / 64, M / 32, S);
    hipLaunchKernelGGL(gemm_part_k, grid, dim3(256), 0, stream, A, B, part, M, N, K, S);
    int MN = M * N;
    hipLaunchKernelGGL(reduce_relu_k, dim3((MN + 255) / 256), dim3(256), 0, stream,
                       part, C, MN, S, relu ? 1 : 0);
}

extern "C" void kernel_launch(void* const* d_in, const int* in_sizes, int n_in,
                              void* d_out, int out_size, void* d_ws, size_t ws_size,
                              hipStream_t stream) {
    const float* xyz   = (const float*)d_in[0];
    const float* feats = (const float*)d_in[1];
    const float* rois  = (const float*)d_in[2];
    const float* w_m1  = (const float*)d_in[3];
    const float* w_m2  = (const float*)d_in[4];
    const float* w_s1  = (const float*)d_in[5];
    const float* w_s2  = (const float*)d_in[6];
    const float* w_c1  = (const float*)d_in[7];
    const float* w_c2  = (const float*)d_in[8];
    const float* w_c3  = (const float*)d_in[9];
    const float* b_c3  = (const float*)d_in[10];
    const float* w_i1  = (const float*)d_in[11];
    const float* w_i2  = (const float*)d_in[12];
    const float* w_i3  = (const float*)d_in[13];
    const float* b_i3  = (const float*)d_in[14];
    const float* w_r1  = (const float*)d_in[15];
    const float* w_r2  = (const float*)d_in[16];
    const float* w_r3  = (const float*)d_in[17];
    const float* b_r3  = (const float*)d_in[18];
    float* out = (float*)d_out;

    char* ws = (char*)d_ws;
    float*    gp     = (float*)(ws + OFF_GP);
    float*    pooled = (float*)(ws + OFF_POOLED);   // == flat (128 x 13824)
    float*    part   = (float*)(ws + OFF_PART);
    int*      cand   = (int*)(ws + OFF_PART);       // reuse (pool phase only)
    int*      ncand  = (int*)(ws + OFF_NCAND);
    ushort_t* w1th   = (ushort_t*)(ws + OFF_W1TH);
    ushort_t* w1tl   = (ushort_t*)(ws + OFF_W1TL);
    ushort_t* w2th   = (ushort_t*)(ws + OFF_W2TH);
    ushort_t* w2tl   = (ushort_t*)(ws + OFF_W2TL);
    float*    t1     = (float*)(ws + OFF_T1);
    float*    sfc    = (float*)(ws + OFF_SFC);
    float*    h1     = (float*)(ws + OFF_H1);
    float*    h2     = (float*)(ws + OFF_H2);

    hipLaunchKernelGGL(grid_points_k, dim3((M_GP + 255) / 256), dim3(256), 0, stream,
                       rois, gp);
    hipLaunchKernelGGL(prep_w_k, dim3(42), dim3(256), 0, stream,
                       w_m1, w_m2, w1th, w1tl, w2th, w2tl);
    hipLaunchKernelGGL(roi_cand_k, dim3(R_ROIS), dim3(64), 0, stream, rois, xyz, cand, ncand);
    hipLaunchKernelGGL(grid_pool_mfma_k, dim3(M_GP / 8), dim3(64), 0, stream,
                       xyz, feats, gp, cand, ncand, w1th, w1tl, w2th, w2tl, pooled);

    // shared FC
    launch_gemm(pooled, w_s1, part, t1, 128, 1024, 13824, true, stream);
    launch_gemm(t1, w_s2, part, sfc, 128, 512, 1024, true, stream);

    // cls head
    launch_gemm(sfc, w_c1, part, h1, 128, 1024, 512, true, stream);
    launch_gemm(h1, w_c2, part, h2, 128, 512, 1024, true, stream);
    hipLaunchKernelGGL(head_out_k, dim3(1), dim3(256), 0, stream, h2, w_c3, b_c3, out, 1, 0);

    // iou head
    launch_gemm(sfc, w_i1, part, h1, 128, 1024, 512, true, stream);
    launch_gemm(h1, w_i2, part, h2, 128, 512, 1024, true, stream);
    hipLaunchKernelGGL(head_out_k, dim3(1), dim3(256), 0, stream, h2, w_i3, b_i3, out, 1, 1);

    // reg head
    launch_gemm(sfc, w_r1, part, h1, 128, 1024, 512, true, stream);
    launch_gemm(h1, w_r2, part, h2, 128, 512, 1024, true, stream);
    hipLaunchKernelGGL(head_out_k, dim3(4), dim3(256), 0, stream, h2, w_r3, b_r3, out, 7, 2);
}

// Round 4
// 388.872 us; speedup vs baseline: 1.8277x; 1.4544x over previous
//
#include <hip/hip_runtime.h>

typedef float  f32x4  __attribute__((ext_vector_type(4)));
typedef __bf16 bf16x8 __attribute__((ext_vector_type(8)));
typedef unsigned short u16x8 __attribute__((ext_vector_type(8)));
typedef unsigned short ushort_t;

#define N_PTS 4096
#define R_ROIS 128
#define M_GP  27648
#define LDS_FENCE() asm volatile("s_waitcnt lgkmcnt(0)" ::: "memory")

// ---------------- workspace layout (bytes), total ~13.8 MB ----------------
static constexpr size_t OFF_GP     = 0;          // 27648*3*4 = 331776
static constexpr size_t OFF_POOLED = 331776;     // 27648*64*4 = 7077888 (== flat 128x13824)
static constexpr size_t OFF_PART   = 7409664;    // 3 MB partials; cand overlaps (pool phase only)
static constexpr size_t OFF_CAND   = OFF_PART;   // 128*4096*4 = 2097152
static constexpr size_t OFF_NCAND  = 10555392;   // 512
static constexpr size_t OFF_W1TH   = 10555904;   // 10752*2
static constexpr size_t OFF_W1TL   = 10577408;   // 10752*2
static constexpr size_t OFF_W2TH   = 10598912;   // 4608*2
static constexpr size_t OFF_W2TL   = 10608128;   // 4608*2 (end 10617344)
static constexpr size_t OFF_T1     = 10617344;   // 128*1024*4 = 524288
static constexpr size_t OFF_SFC    = 11141632;   // 128*512*4 = 262144
static constexpr size_t OFF_H1S    = 11403776;   // 3*128*1024*4 = 1572864
static constexpr size_t OFF_H2S    = 12976640;   // 3*128*512*4 = 786432 (end 13763072)

static __device__ inline ushort_t f2bf(float f) {
    unsigned int u = __float_as_uint(f);
    unsigned int r = u + 0x7FFFu + ((u >> 16) & 1u);
    return (ushort_t)(r >> 16);
}
static __device__ inline float bf2f(ushort_t h) {
    return __uint_as_float(((unsigned int)h) << 16);
}

// ---------------- grid points ----------------
__global__ __launch_bounds__(256) void grid_points_k(const float* __restrict__ rois,
                                                     float* __restrict__ gp) {
    int m = blockIdx.x * 256 + threadIdx.x;
    if (m >= M_GP) return;
    int r = m / 216, t = m % 216;
    int gi = t / 36, gj = (t / 6) % 6, gk = t % 6;
    const float* roi = rois + r * 7;
    float sx = roi[3], sy = roi[4], sz = roi[5];
    float lx = ((float)gi + 0.5f) / 6.0f * sx - sx * 0.5f;
    float ly = ((float)gj + 0.5f) / 6.0f * sy - sy * 0.5f;
    float lz = ((float)gk + 0.5f) / 6.0f * sz - sz * 0.5f;
    float c = cosf(roi[6]), s = sinf(roi[6]);
    gp[m * 3 + 0] = lx * c - ly * s + roi[0];
    gp[m * 3 + 1] = lx * s + ly * c + roi[1];
    gp[m * 3 + 2] = lz + roi[2];
}

// ---------------- weight prep: PERMUTED transpose + pad + hi/lo bf16 ----
// K-permutation: p<128 -> w1 row (3+p)  (feats channel p)
//                p=128..130 -> w1 row (p-128)  (rel x,y,z)
//                p>=131 -> 0
__global__ __launch_bounds__(256) void prep_w_k(const float* __restrict__ w1,
                                                const float* __restrict__ w2,
                                                ushort_t* __restrict__ w1th,
                                                ushort_t* __restrict__ w1tl,
                                                ushort_t* __restrict__ w2th,
                                                ushort_t* __restrict__ w2tl) {
    int t = blockIdx.x * 256 + threadIdx.x;
    if (t < 10752) {
        int col = t / 168, p = t % 168;
        float v = (p < 128) ? w1[(3 + p) * 64 + col]
                : (p < 131) ? w1[(p - 128) * 64 + col] : 0.f;
        ushort_t hi = f2bf(v);
        w1th[t] = hi;
        w1tl[t] = f2bf(v - bf2f(hi));
    }
    if (t < 4608) {
        int col = t / 72, k = t % 72;
        float v = (k < 64) ? w2[k * 64 + col] : 0.f;
        ushort_t hi = f2bf(v);
        w2th[t] = hi;
        w2tl[t] = f2bf(v - bf2f(hi));
    }
}

// ---------------- per-RoI candidate lists (ascending index order) -------
__global__ __launch_bounds__(64) void roi_cand_k(const float* __restrict__ rois,
                                                 const float* __restrict__ xyz,
                                                 int* __restrict__ cand,
                                                 int* __restrict__ ncand) {
    int r = blockIdx.x;
    int lane = threadIdx.x;
    const float* roi = rois + r * 7;
    float cx = roi[0], cy = roi[1], cz = roi[2];
    float sx = roi[3], sy = roi[4], sz = roi[5];
    float Rc = 0.8f + 0.4166667f * sqrtf(sx * sx + sy * sy + sz * sz) + 0.01f;
    float Rc2 = Rc * Rc;
    int* cl = cand + r * N_PTS;
    int cnt = 0;
    for (int base = 0; base < N_PTS; base += 64) {
        int i = base + lane;
        float dx = xyz[i * 3 + 0] - cx;
        float dy = xyz[i * 3 + 1] - cy;
        float dz = xyz[i * 3 + 2] - cz;
        bool in = dx * dx + dy * dy + dz * dz < Rc2;
        unsigned long long ball = __ballot(in);
        int before = __popcll(ball & ((1ull << lane) - 1ull));
        if (in) cl[cnt + before] = i;
        cnt += __popcll(ball);
    }
    if (lane == 0) ncand[r] = cnt;
}

// ---------------- search + split-bf16 MFMA point-MLP + maxpool ----------
// one wave per block; 8 grid points per wave; A-frags direct from feats
__global__ __launch_bounds__(64) void grid_pool_mfma_k(
    const float* __restrict__ xyz, const float* __restrict__ feats,
    const float* __restrict__ gp, const int* __restrict__ cand,
    const int* __restrict__ ncand,
    const ushort_t* __restrict__ w1th, const ushort_t* __restrict__ w1tl,
    const ushort_t* __restrict__ w2th, const ushort_t* __restrict__ w2tl,
    float* __restrict__ pooled) {
    __shared__ __attribute__((aligned(16))) ushort_t s_hh[1152];  // [16][72]
    __shared__ __attribute__((aligned(16))) ushort_t s_hl[1152];
    __shared__ int s_idx[16];

    int lane = threadIdx.x;
    const float R2 = (float)(0.8 * 0.8);
    int row = lane & 15, grp = lane >> 4;

    for (int it = 0; it < 8; it++) {
        int m = blockIdx.x * 8 + it;
        int r = m / 216;
        float gx = gp[m * 3 + 0], gy = gp[m * 3 + 1], gz = gp[m * 3 + 2];

        // ---- search first <=16 in-radius indices over RoI candidate list
        int nc = ncand[r];
        const int* cl = cand + (size_t)r * N_PTS;
        int count = 0;
        for (int base = 0; base < nc; base += 64) {
            int t = base + lane;
            bool in = false;
            int i = 0;
            if (t < nc) {
                i = cl[t];
                float dx = xyz[i * 3 + 0] - gx;
                float dy = xyz[i * 3 + 1] - gy;
                float dz = xyz[i * 3 + 2] - gz;
                in = dx * dx + dy * dy + dz * dz < R2;
            }
            unsigned long long ball = __ballot(in);
            int before = __popcll(ball & ((1ull << lane) - 1ull));
            int pos = count + before;
            if (in && pos < 16) s_idx[pos] = i;
            count += __popcll(ball);
            if (count >= 16) break;
        }
        int c = min(count, 16);
        LDS_FENCE();

        if (c == 0) {
            pooled[(size_t)m * 64 + lane] = 0.f;
            continue;
        }
        if (lane == 0) {                 // pad with first valid index
            int f = s_idx[0];
            for (int p = c; p < 16; p++) s_idx[p] = f;
        }
        LDS_FENCE();

        // each lane owns neighbor row = lane&15, k-chunk = grp*8
        int pi = s_idx[row];
        float rx = xyz[pi * 3 + 0] - gx;
        float ry = xyz[pi * 3 + 1] - gy;
        float rz = xyz[pi * 3 + 2] - gz;

        // ---- stage 1: (16x160) @ (160x64); A direct from feats (permuted K)
        f32x4 a0 = {0.f, 0.f, 0.f, 0.f}, a1 = a0, a2 = a0, a3 = a0;
#pragma unroll
        for (int ks = 0; ks < 4; ks++) {
            const float* fp = feats + (size_t)pi * 128 + ks * 32 + grp * 8;
            float fv[8];
            *(float4*)&fv[0] = *(const float4*)fp;
            *(float4*)&fv[4] = *(const float4*)(fp + 4);
            u16x8 uh, ul;
#pragma unroll
            for (int i = 0; i < 8; i++) {
                ushort_t h = f2bf(fv[i]);
                uh[i] = h;
                ul[i] = f2bf(fv[i] - bf2f(h));
            }
            bf16x8 ah = __builtin_bit_cast(bf16x8, uh);
            bf16x8 al = __builtin_bit_cast(bf16x8, ul);
#pragma unroll
            for (int nt = 0; nt < 4; nt++) {
                int bo = (nt * 16 + row) * 168 + ks * 32 + grp * 8;
                bf16x8 bh = *(const bf16x8*)&w1th[bo];
                bf16x8 bl = *(const bf16x8*)&w1tl[bo];
                f32x4 acc = (nt == 0) ? a0 : (nt == 1) ? a1 : (nt == 2) ? a2 : a3;
                acc = __builtin_amdgcn_mfma_f32_16x16x32_bf16(ah, bh, acc, 0, 0, 0);
                acc = __builtin_amdgcn_mfma_f32_16x16x32_bf16(al, bh, acc, 0, 0, 0);
                acc = __builtin_amdgcn_mfma_f32_16x16x32_bf16(ah, bl, acc, 0, 0, 0);
                if (nt == 0) a0 = acc; else if (nt == 1) a1 = acc;
                else if (nt == 2) a2 = acc; else a3 = acc;
            }
        }
        {   // ks = 4: channels 128..130 = rel xyz (grp 0 lanes), rest zero
            u16x8 uh = {0, 0, 0, 0, 0, 0, 0, 0}, ul = uh;
            if (grp == 0) {
                ushort_t h0 = f2bf(rx), h1 = f2bf(ry), h2 = f2bf(rz);
                uh[0] = h0; ul[0] = f2bf(rx - bf2f(h0));
                uh[1] = h1; ul[1] = f2bf(ry - bf2f(h1));
                uh[2] = h2; ul[2] = f2bf(rz - bf2f(h2));
            }
            bf16x8 ah = __builtin_bit_cast(bf16x8, uh);
            bf16x8 al = __builtin_bit_cast(bf16x8, ul);
#pragma unroll
            for (int nt = 0; nt < 4; nt++) {
                int bo = (nt * 16 + row) * 168 + 128 + grp * 8;
                bf16x8 bh = *(const bf16x8*)&w1th[bo];
                bf16x8 bl = *(const bf16x8*)&w1tl[bo];
                f32x4 acc = (nt == 0) ? a0 : (nt == 1) ? a1 : (nt == 2) ? a2 : a3;
                acc = __builtin_amdgcn_mfma_f32_16x16x32_bf16(ah, bh, acc, 0, 0, 0);
                acc = __builtin_amdgcn_mfma_f32_16x16x32_bf16(al, bh, acc, 0, 0, 0);
                acc = __builtin_amdgcn_mfma_f32_16x16x32_bf16(ah, bl, acc, 0, 0, 0);
                if (nt == 0) a0 = acc; else if (nt == 1) a1 = acc;
                else if (nt == 2) a2 = acc; else a3 = acc;
            }
        }
        // relu -> h1 hi/lo bf16 LDS: D row=(grp*4+reg), col=(nt*16+row)
#pragma unroll
        for (int reg = 0; reg < 4; reg++) {
            int hrow = grp * 4 + reg;
#pragma unroll
            for (int nt = 0; nt < 4; nt++) {
                f32x4 pv = (nt == 0) ? a0 : (nt == 1) ? a1 : (nt == 2) ? a2 : a3;
                float v = fmaxf(pv[reg], 0.f);
                ushort_t hh = f2bf(v);
                s_hh[hrow * 72 + nt * 16 + row] = hh;
                s_hl[hrow * 72 + nt * 16 + row] = f2bf(v - bf2f(hh));
            }
        }
        LDS_FENCE();

        // ---- stage 2: (16x64) @ (64x64), 2 k-steps x 4 n-tiles x 3 terms
        f32x4 p0 = {0.f, 0.f, 0.f, 0.f}, p1 = p0, p2 = p0, p3 = p0;
#pragma unroll
        for (int ks = 0; ks < 2; ks++) {
            int ao = row * 72 + ks * 32 + grp * 8;
            bf16x8 ah = *(const bf16x8*)&s_hh[ao];
            bf16x8 al = *(const bf16x8*)&s_hl[ao];
#pragma unroll
            for (int nt = 0; nt < 4; nt++) {
                int bo = (nt * 16 + row) * 72 + ks * 32 + grp * 8;
                bf16x8 bh = *(const bf16x8*)&w2th[bo];
                bf16x8 bl = *(const bf16x8*)&w2tl[bo];
                f32x4 acc = (nt == 0) ? p0 : (nt == 1) ? p1 : (nt == 2) ? p2 : p3;
                acc = __builtin_amdgcn_mfma_f32_16x16x32_bf16(ah, bh, acc, 0, 0, 0);
                acc = __builtin_amdgcn_mfma_f32_16x16x32_bf16(al, bh, acc, 0, 0, 0);
                acc = __builtin_amdgcn_mfma_f32_16x16x32_bf16(ah, bl, acc, 0, 0, 0);
                if (nt == 0) p0 = acc; else if (nt == 1) p1 = acc;
                else if (nt == 2) p2 = acc; else p3 = acc;
            }
        }
        // ---- relu + max over 16 rows (padded rows duplicate row0) ----
#pragma unroll
        for (int nt = 0; nt < 4; nt++) {
            f32x4 pv = (nt == 0) ? p0 : (nt == 1) ? p1 : (nt == 2) ? p2 : p3;
            float mv = fmaxf(fmaxf(fmaxf(pv[0], pv[1]), fmaxf(pv[2], pv[3])), 0.f);
            mv = fmaxf(mv, __shfl_xor(mv, 16));
            mv = fmaxf(mv, __shfl_xor(mv, 32));
            if (grp == 0) pooled[(size_t)m * 64 + nt * 16 + row] = mv;
        }
    }
}

// ---------------- split-K tiled fp32 GEMM: partials ----------------
__global__ __launch_bounds__(256) void gemm_part_k(
    const float* __restrict__ A, const float* __restrict__ B,
    float* __restrict__ P, int M, int N, int Kt, int S) {
    __shared__ float As[32][33];
    __shared__ float Bs[32][64];
    int tid = threadIdx.x;
    int s = blockIdx.z;
    int klen = Kt / S;
    int k0 = s * klen;
    int m0 = blockIdx.y * 32;
    int n0 = blockIdx.x * 64;
    int tx = tid % 16, ty = tid / 16;

    float acc[2][4];
#pragma unroll
    for (int i = 0; i < 2; i++)
#pragma unroll
        for (int j = 0; j < 4; j++) acc[i][j] = 0.f;

    for (int kt = 0; kt < klen; kt += 32) {
        {
            int mm = tid / 8;
            int kk = (tid % 8) * 4;
            const float* ap = A + (size_t)(m0 + mm) * Kt + k0 + kt + kk;
            float4 v = *(const float4*)ap;
            As[kk + 0][mm] = v.x; As[kk + 1][mm] = v.y;
            As[kk + 2][mm] = v.z; As[kk + 3][mm] = v.w;
        }
        {
            int kk = tid / 16;
            int nn = (tid % 16) * 4;
            const float4 v0 = *(const float4*)(B + (size_t)(k0 + kt + kk) * N + n0 + nn);
            *(float4*)&Bs[kk][nn] = v0;
            const float4 v1 = *(const float4*)(B + (size_t)(k0 + kt + kk + 16) * N + n0 + nn);
            *(float4*)&Bs[kk + 16][nn] = v1;
        }
        __syncthreads();
#pragma unroll
        for (int kk = 0; kk < 32; kk++) {
            float a0 = As[kk][ty * 2 + 0];
            float a1 = As[kk][ty * 2 + 1];
            float4 b = *(const float4*)&Bs[kk][tx * 4];
            acc[0][0] += a0 * b.x; acc[0][1] += a0 * b.y;
            acc[0][2] += a0 * b.z; acc[0][3] += a0 * b.w;
            acc[1][0] += a1 * b.x; acc[1][1] += a1 * b.y;
            acc[1][2] += a1 * b.z; acc[1][3] += a1 * b.w;
        }
        __syncthreads();
    }
#pragma unroll
    for (int i = 0; i < 2; i++) {
        int mrow = m0 + ty * 2 + i;
        float* pp = P + ((size_t)s * M + mrow) * N + n0 + tx * 4;
#pragma unroll
        for (int j = 0; j < 4; j++) pp[j] = acc[i][j];
    }
}

// ---- 3-head variant: blockIdx.z = head*S + s; A/B selected per head ----
__global__ __launch_bounds__(256) void head_gemm_k(
    const float* __restrict__ A0, const float* __restrict__ A1,
    const float* __restrict__ A2, const float* __restrict__ B0,
    const float* __restrict__ B1, const float* __restrict__ B2,
    float* __restrict__ P, int M, int N, int Kt, int S) {
    __shared__ float As[32][33];
    __shared__ float Bs[32][64];
    int tid = threadIdx.x;
    int z = blockIdx.z;
    int head = z / S, s = z % S;
    const float* A = (head == 0) ? A0 : (head == 1) ? A1 : A2;
    const float* B = (head == 0) ? B0 : (head == 1) ? B1 : B2;
    int klen = Kt / S;
    int k0 = s * klen;
    int m0 = blockIdx.y * 32;
    int n0 = blockIdx.x * 64;
    int tx = tid % 16, ty = tid / 16;

    float acc[2][4];
#pragma unroll
    for (int i = 0; i < 2; i++)
#pragma unroll
        for (int j = 0; j < 4; j++) acc[i][j] = 0.f;

    for (int kt = 0; kt < klen; kt += 32) {
        {
            int mm = tid / 8;
            int kk = (tid % 8) * 4;
            const float* ap = A + (size_t)(m0 + mm) * Kt + k0 + kt + kk;
            float4 v = *(const float4*)ap;
            As[kk + 0][mm] = v.x; As[kk + 1][mm] = v.y;
            As[kk + 2][mm] = v.z; As[kk + 3][mm] = v.w;
        }
        {
            int kk = tid / 16;
            int nn = (tid % 16) * 4;
            const float4 v0 = *(const float4*)(B + (size_t)(k0 + kt + kk) * N + n0 + nn);
            *(float4*)&Bs[kk][nn] = v0;
            const float4 v1 = *(const float4*)(B + (size_t)(k0 + kt + kk + 16) * N + n0 + nn);
            *(float4*)&Bs[kk + 16][nn] = v1;
        }
        __syncthreads();
#pragma unroll
        for (int kk = 0; kk < 32; kk++) {
            float a0 = As[kk][ty * 2 + 0];
            float a1 = As[kk][ty * 2 + 1];
            float4 b = *(const float4*)&Bs[kk][tx * 4];
            acc[0][0] += a0 * b.x; acc[0][1] += a0 * b.y;
            acc[0][2] += a0 * b.z; acc[0][3] += a0 * b.w;
            acc[1][0] += a1 * b.x; acc[1][1] += a1 * b.y;
            acc[1][2] += a1 * b.z; acc[1][3] += a1 * b.w;
        }
        __syncthreads();
    }
#pragma unroll
    for (int i = 0; i < 2; i++) {
        int mrow = m0 + ty * 2 + i;
        float* pp = P + ((size_t)(head * S + s) * M + mrow) * N + n0 + tx * 4;
#pragma unroll
        for (int j = 0; j < 4; j++) pp[j] = acc[i][j];
    }
}

__global__ __launch_bounds__(256) void reduce_relu_k(const float* __restrict__ P,
                                                     float* __restrict__ C,
                                                     int MN, int S, int doRelu) {
    int i = blockIdx.x * 256 + threadIdx.x;
    if (i >= MN) return;
    float v = 0.f;
    for (int s = 0; s < S; s++) v += P[(size_t)s * MN + i];
    C[i] = doRelu ? fmaxf(v, 0.f) : v;
}

// 3-head reduce: C is head-major contiguous (3 x MNper)
__global__ __launch_bounds__(256) void heads_reduce_k(const float* __restrict__ P,
                                                      float* __restrict__ C,
                                                      int MNper, int S) {
    int i = blockIdx.x * 256 + threadIdx.x;
    if (i >= 3 * MNper) return;
    int head = i / MNper, j = i % MNper;
    float v = 0.f;
    for (int s = 0; s < S; s++) v += P[((size_t)(head * S + s)) * MNper + j];
    C[i] = fmaxf(v, 0.f);
}

// ---------------- final head projections (merged) ----------------
__global__ __launch_bounds__(256) void head_out3_k(
    const float* __restrict__ h2s, const float* __restrict__ w_c3,
    const float* __restrict__ w_i3, const float* __restrict__ w_r3,
    const float* __restrict__ b_c3, const float* __restrict__ b_i3,
    const float* __restrict__ b_r3, float* __restrict__ out) {
    int t = blockIdx.x * 256 + threadIdx.x;
    if (t >= 128 * 9) return;
    int r = t / 9, col = t % 9;
    int head = (col == 0) ? 0 : (col == 1) ? 1 : 2;
    int p = (col < 2) ? 0 : col - 2;
    int Pn = (head == 2) ? 7 : 1;
    const float* h2 = h2s + (size_t)head * (128 * 512) + (size_t)r * 512;
    const float* w3 = (head == 0) ? w_c3 : (head == 1) ? w_i3 : w_r3;
    float acc = ((head == 0) ? b_c3 : (head == 1) ? b_i3 : b_r3)[p];
    for (int j = 0; j < 512; j++) acc += h2[j] * w3[j * Pn + p];
    out[r * 9 + col] = acc;
}

static void launch_gemm(const float* A, const float* B, float* part, float* C,
                        int M, int N, int K, hipStream_t stream) {
    const int S = 4;
    dim3 grid(N / 64, M / 32, S);
    hipLaunchKernelGGL(gemm_part_k, grid, dim3(256), 0, stream, A, B, part, M, N, K, S);
    int MN = M * N;
    hipLaunchKernelGGL(reduce_relu_k, dim3((MN + 255) / 256), dim3(256), 0, stream,
                       part, C, MN, S, 1);
}

extern "C" void kernel_launch(void* const* d_in, const int* in_sizes, int n_in,
                              void* d_out, int out_size, void* d_ws, size_t ws_size,
                              hipStream_t stream) {
    const float* xyz   = (const float*)d_in[0];
    const float* feats = (const float*)d_in[1];
    const float* rois  = (const float*)d_in[2];
    const float* w_m1  = (const float*)d_in[3];
    const float* w_m2  = (const float*)d_in[4];
    const float* w_s1  = (const float*)d_in[5];
    const float* w_s2  = (const float*)d_in[6];
    const float* w_c1  = (const float*)d_in[7];
    const float* w_c2  = (const float*)d_in[8];
    const float* w_c3  = (const float*)d_in[9];
    const float* b_c3  = (const float*)d_in[10];
    const float* w_i1  = (const float*)d_in[11];
    const float* w_i2  = (const float*)d_in[12];
    const float* w_i3  = (const float*)d_in[13];
    const float* b_i3  = (const float*)d_in[14];
    const float* w_r1  = (const float*)d_in[15];
    const float* w_r2  = (const float*)d_in[16];
    const float* w_r3  = (const float*)d_in[17];
    const float* b_r3  = (const float*)d_in[18];
    float* out = (float*)d_out;

    char* ws = (char*)d_ws;
    float*    gp     = (float*)(ws + OFF_GP);
    float*    pooled = (float*)(ws + OFF_POOLED);   // == flat (128 x 13824)
    float*    part   = (float*)(ws + OFF_PART);
    int*      cand   = (int*)(ws + OFF_CAND);       // overlaps part (pool phase only)
    int*      ncand  = (int*)(ws + OFF_NCAND);
    ushort_t* w1th   = (ushort_t*)(ws + OFF_W1TH);
    ushort_t* w1tl   = (ushort_t*)(ws + OFF_W1TL);
    ushort_t* w2th   = (ushort_t*)(ws + OFF_W2TH);
    ushort_t* w2tl   = (ushort_t*)(ws + OFF_W2TL);
    float*    t1     = (float*)(ws + OFF_T1);
    float*    sfc    = (float*)(ws + OFF_SFC);
    float*    h1s    = (float*)(ws + OFF_H1S);
    float*    h2s    = (float*)(ws + OFF_H2S);

    hipLaunchKernelGGL(grid_points_k, dim3((M_GP + 255) / 256), dim3(256), 0, stream,
                       rois, gp);
    hipLaunchKernelGGL(prep_w_k, dim3(42), dim3(256), 0, stream,
                       w_m1, w_m2, w1th, w1tl, w2th, w2tl);
    hipLaunchKernelGGL(roi_cand_k, dim3(R_ROIS), dim3(64), 0, stream, rois, xyz, cand, ncand);
    hipLaunchKernelGGL(grid_pool_mfma_k, dim3(M_GP / 8), dim3(64), 0, stream,
                       xyz, feats, gp, cand, ncand, w1th, w1tl, w2th, w2tl, pooled);

    // shared FC (fp32)
    launch_gemm(pooled, w_s1, part, t1, 128, 1024, 13824, stream);
    launch_gemm(t1, w_s2, part, sfc, 128, 512, 1024, stream);

    // heads layer 1 (merged): sfc @ {w_c1,w_i1,w_r1} -> h1s
    {
        const int S = 2;
        dim3 grid(1024 / 64, 128 / 32, 3 * S);
        hipLaunchKernelGGL(head_gemm_k, grid, dim3(256), 0, stream,
                           sfc, sfc, sfc, w_c1, w_i1, w_r1, part, 128, 1024, 512, S);
        int MNper = 128 * 1024;
        hipLaunchKernelGGL(heads_reduce_k, dim3((3 * MNper + 255) / 256), dim3(256), 0,
                           stream, part, h1s, MNper, S);
    }
    // heads layer 2 (merged): h1s @ {w_c2,w_i2,w_r2} -> h2s
    {
        const int S = 2;
        dim3 grid(512 / 64, 128 / 32, 3 * S);
        hipLaunchKernelGGL(head_gemm_k, grid, dim3(256), 0, stream,
                           h1s, h1s + 131072, h1s + 262144, w_c2, w_i2, w_r2,
                           part, 128, 512, 1024, S);
        int MNper = 128 * 512;
        hipLaunchKernelGGL(heads_reduce_k, dim3((3 * MNper + 255) / 256), dim3(256), 0,
                           stream, part, h2s, MNper, S);
    }
    // final projections (merged)
    hipLaunchKernelGGL(head_out3_k, dim3((128 * 9 + 255) / 256), dim3(256), 0, stream,
                       h2s, w_c3, w_i3, w_r3, b_c3, b_i3, b_r3, out);
}

// Round 5
// 373.814 us; speedup vs baseline: 1.9013x; 1.0403x over previous
//
#include <hip/hip_runtime.h>

typedef float  f32x4  __attribute__((ext_vector_type(4)));
typedef __bf16 bf16x8 __attribute__((ext_vector_type(8)));
typedef unsigned short ushort_t;

#define N_PTS 4096
#define R_ROIS 128
#define M_GP  27648
#define LDS_FENCE() asm volatile("s_waitcnt lgkmcnt(0)" ::: "memory")

// ---------------- workspace layout (bytes), total 13,763,072 ----------------
static constexpr size_t OFF_GP     = 0;          // 331776
static constexpr size_t OFF_POOLED = 331776;     // 27648*64*4 = 7077888 (== flat 128x13824)
static constexpr size_t OFF_PART   = 7409664;    // 3 MB partials; cand overlaps (pool phase)
static constexpr size_t OFF_CAND   = OFF_PART;   // 128*4096*4 = 2097152
static constexpr size_t OFF_NCAND  = 10555392;   // 512
static constexpr size_t OFF_W1TH   = 10555904;   // 10752*2
static constexpr size_t OFF_W1TL   = 10577408;   // 10752*2
static constexpr size_t OFF_W2TH   = 10598912;   // 4608*2
static constexpr size_t OFF_W2TL   = 10608128;   // 4608*2 (end 10617344)
// FHI/FLO live only during pool phase; they overlap T1/SFC/H1S which are
// written strictly after grid_pool completes (stream-ordered).
static constexpr size_t OFF_FHI    = 10617344;   // 4096*128*2 = 1048576
static constexpr size_t OFF_FLO    = 11665920;   // 1048576 (end 12714496)
static constexpr size_t OFF_T1     = 10617344;   // 524288
static constexpr size_t OFF_SFC    = 11141632;   // 262144
static constexpr size_t OFF_H1S    = 11403776;   // 3*128*1024*4 = 1572864
static constexpr size_t OFF_H2S    = 12976640;   // 3*128*512*4 = 786432 (end 13763072)

static __device__ inline ushort_t f2bf(float f) {
    unsigned int u = __float_as_uint(f);
    unsigned int r = u + 0x7FFFu + ((u >> 16) & 1u);
    return (ushort_t)(r >> 16);
}
static __device__ inline float bf2f(ushort_t h) {
    return __uint_as_float(((unsigned int)h) << 16);
}

// ---------------- grid points ----------------
__global__ __launch_bounds__(256) void grid_points_k(const float* __restrict__ rois,
                                                     float* __restrict__ gp) {
    int m = blockIdx.x * 256 + threadIdx.x;
    if (m >= M_GP) return;
    int r = m / 216, t = m % 216;
    int gi = t / 36, gj = (t / 6) % 6, gk = t % 6;
    const float* roi = rois + r * 7;
    float sx = roi[3], sy = roi[4], sz = roi[5];
    float lx = ((float)gi + 0.5f) / 6.0f * sx - sx * 0.5f;
    float ly = ((float)gj + 0.5f) / 6.0f * sy - sy * 0.5f;
    float lz = ((float)gk + 0.5f) / 6.0f * sz - sz * 0.5f;
    float c = cosf(roi[6]), s = sinf(roi[6]);
    gp[m * 3 + 0] = lx * c - ly * s + roi[0];
    gp[m * 3 + 1] = lx * s + ly * c + roi[1];
    gp[m * 3 + 2] = lz + roi[2];
}

// ---------------- feats -> hi/lo bf16 (pre-converted once) ----------------
__global__ __launch_bounds__(256) void prep_feats_k(const float* __restrict__ feats,
                                                    ushort_t* __restrict__ fhi,
                                                    ushort_t* __restrict__ flo) {
    int i = blockIdx.x * 256 + threadIdx.x;
    if (i >= N_PTS * 128) return;
    float v = feats[i];
    __bf16 h = (__bf16)v;
    fhi[i] = __builtin_bit_cast(ushort_t, h);
    __bf16 l = (__bf16)(v - (float)h);
    flo[i] = __builtin_bit_cast(ushort_t, l);
}

// ---------------- weight prep: PERMUTED transpose + pad + hi/lo bf16 ----
__global__ __launch_bounds__(256) void prep_w_k(const float* __restrict__ w1,
                                                const float* __restrict__ w2,
                                                ushort_t* __restrict__ w1th,
                                                ushort_t* __restrict__ w1tl,
                                                ushort_t* __restrict__ w2th,
                                                ushort_t* __restrict__ w2tl) {
    int t = blockIdx.x * 256 + threadIdx.x;
    if (t < 10752) {
        int col = t / 168, p = t % 168;
        float v = (p < 128) ? w1[(3 + p) * 64 + col]
                : (p < 131) ? w1[(p - 128) * 64 + col] : 0.f;
        ushort_t hi = f2bf(v);
        w1th[t] = hi;
        w1tl[t] = f2bf(v - bf2f(hi));
    }
    if (t < 4608) {
        int col = t / 72, k = t % 72;
        float v = (k < 64) ? w2[k * 64 + col] : 0.f;
        ushort_t hi = f2bf(v);
        w2th[t] = hi;
        w2tl[t] = f2bf(v - bf2f(hi));
    }
}

// ---------------- per-RoI candidate lists (ascending index order) -------
__global__ __launch_bounds__(64) void roi_cand_k(const float* __restrict__ rois,
                                                 const float* __restrict__ xyz,
                                                 int* __restrict__ cand,
                                                 int* __restrict__ ncand) {
    int r = blockIdx.x;
    int lane = threadIdx.x;
    const float* roi = rois + r * 7;
    float cx = roi[0], cy = roi[1], cz = roi[2];
    float sx = roi[3], sy = roi[4], sz = roi[5];
    float Rc = 0.8f + 0.4166667f * sqrtf(sx * sx + sy * sy + sz * sz) + 0.01f;
    float Rc2 = Rc * Rc;
    int* cl = cand + r * N_PTS;
    int cnt = 0;
    for (int base = 0; base < N_PTS; base += 64) {
        int i = base + lane;
        float dx = xyz[i * 3 + 0] - cx;
        float dy = xyz[i * 3 + 1] - cy;
        float dz = xyz[i * 3 + 2] - cz;
        bool in = dx * dx + dy * dy + dz * dz < Rc2;
        unsigned long long ball = __ballot(in);
        int before = __popcll(ball & ((1ull << lane) - 1ull));
        if (in) cl[cnt + before] = i;
        cnt += __popcll(ball);
    }
    if (lane == 0) ncand[r] = cnt;
}

// ---------------- search + split-bf16 MFMA point-MLP + maxpool ----------
// one wave per block; 4 grid points per wave, B-fragments shared in regs
__global__ __launch_bounds__(64) void grid_pool_mfma4_k(
    const float* __restrict__ xyz,
    const ushort_t* __restrict__ fhi, const ushort_t* __restrict__ flo,
    const float* __restrict__ gp, const int* __restrict__ cand,
    const int* __restrict__ ncand,
    const ushort_t* __restrict__ w1th, const ushort_t* __restrict__ w1tl,
    const ushort_t* __restrict__ w2th, const ushort_t* __restrict__ w2tl,
    float* __restrict__ pooled) {
    __shared__ __attribute__((aligned(16))) ushort_t s_hh[4][1152];  // [16][72]
    __shared__ __attribute__((aligned(16))) ushort_t s_hl[4][1152];
    __shared__ int s_idx[4][16];

    int lane = threadIdx.x;
    const float R2 = (float)(0.8 * 0.8);
    int row = lane & 15, grp = lane >> 4;
    int m0 = blockIdx.x * 4;

    bool empty[4];
    float gxv[4], gyv[4], gzv[4];

    // ---- search per gp: first <=16 in-radius indices (ascending order) ----
#pragma unroll
    for (int g = 0; g < 4; g++) {
        int m = m0 + g;
        int r = m / 216;
        float gx = gp[m * 3 + 0], gy = gp[m * 3 + 1], gz = gp[m * 3 + 2];
        gxv[g] = gx; gyv[g] = gy; gzv[g] = gz;
        int nc = ncand[r];
        const int* cl = cand + (size_t)r * N_PTS;
        int count = 0;
        for (int base = 0; base < nc; base += 64) {
            int t = base + lane;
            bool in = false;
            int i = 0;
            if (t < nc) {
                i = cl[t];
                float dx = xyz[i * 3 + 0] - gx;
                float dy = xyz[i * 3 + 1] - gy;
                float dz = xyz[i * 3 + 2] - gz;
                in = dx * dx + dy * dy + dz * dz < R2;
            }
            unsigned long long ball = __ballot(in);
            int before = __popcll(ball & ((1ull << lane) - 1ull));
            int pos = count + before;
            if (in && pos < 16) s_idx[g][pos] = i;
            count += __popcll(ball);
            if (count >= 16) break;
        }
        int c = min(count, 16);
        empty[g] = (c == 0);
        if (lane == 0) {
            if (c == 0) {
                for (int p = 0; p < 16; p++) s_idx[g][p] = 0;
            } else {
                LDS_FENCE();
                int f = s_idx[g][0];
                for (int p = c; p < 16; p++) s_idx[g][p] = f;
            }
        }
    }
    LDS_FENCE();

    // per-lane neighbor index and rel for each gp (row = lane&15)
    int pi[4];
    float rx[4], ry[4], rz[4];
#pragma unroll
    for (int g = 0; g < 4; g++) {
        pi[g] = s_idx[g][row];
        rx[g] = xyz[pi[g] * 3 + 0] - gxv[g];
        ry[g] = xyz[pi[g] * 3 + 1] - gyv[g];
        rz[g] = xyz[pi[g] * 3 + 2] - gzv[g];
    }

    // ---- stage 1: (16x160)@(160x64) per gp; B-frags shared across 4 gps ----
    f32x4 acc[4][4];
#pragma unroll
    for (int g = 0; g < 4; g++)
#pragma unroll
        for (int nt = 0; nt < 4; nt++) acc[g][nt] = {0.f, 0.f, 0.f, 0.f};

#pragma unroll
    for (int ks = 0; ks < 4; ks++) {
        bf16x8 ah[4], al[4];
#pragma unroll
        for (int g = 0; g < 4; g++) {
            size_t fo = (size_t)pi[g] * 128 + ks * 32 + grp * 8;
            ah[g] = *(const bf16x8*)&fhi[fo];
            al[g] = *(const bf16x8*)&flo[fo];
        }
#pragma unroll
        for (int nt = 0; nt < 4; nt++) {
            int bo = (nt * 16 + row) * 168 + ks * 32 + grp * 8;
            bf16x8 bh = *(const bf16x8*)&w1th[bo];
            bf16x8 bl = *(const bf16x8*)&w1tl[bo];
#pragma unroll
            for (int g = 0; g < 4; g++) {
                acc[g][nt] = __builtin_amdgcn_mfma_f32_16x16x32_bf16(ah[g], bh, acc[g][nt], 0, 0, 0);
                acc[g][nt] = __builtin_amdgcn_mfma_f32_16x16x32_bf16(al[g], bh, acc[g][nt], 0, 0, 0);
                acc[g][nt] = __builtin_amdgcn_mfma_f32_16x16x32_bf16(ah[g], bl, acc[g][nt], 0, 0, 0);
            }
        }
    }
    {   // ks = 4: channels 128..130 = rel xyz (grp 0 lanes), rest zero
        bf16x8 ah[4], al[4];
#pragma unroll
        for (int g = 0; g < 4; g++) {
            bf16x8 zh = {};
            bf16x8 zl = {};
            if (grp == 0) {
                __bf16 h0 = (__bf16)rx[g], h1 = (__bf16)ry[g], h2 = (__bf16)rz[g];
                zh[0] = h0; zl[0] = (__bf16)(rx[g] - (float)h0);
                zh[1] = h1; zl[1] = (__bf16)(ry[g] - (float)h1);
                zh[2] = h2; zl[2] = (__bf16)(rz[g] - (float)h2);
            }
            ah[g] = zh; al[g] = zl;
        }
#pragma unroll
        for (int nt = 0; nt < 4; nt++) {
            int bo = (nt * 16 + row) * 168 + 128 + grp * 8;
            bf16x8 bh = *(const bf16x8*)&w1th[bo];
            bf16x8 bl = *(const bf16x8*)&w1tl[bo];
#pragma unroll
            for (int g = 0; g < 4; g++) {
                acc[g][nt] = __builtin_amdgcn_mfma_f32_16x16x32_bf16(ah[g], bh, acc[g][nt], 0, 0, 0);
                acc[g][nt] = __builtin_amdgcn_mfma_f32_16x16x32_bf16(al[g], bh, acc[g][nt], 0, 0, 0);
                acc[g][nt] = __builtin_amdgcn_mfma_f32_16x16x32_bf16(ah[g], bl, acc[g][nt], 0, 0, 0);
            }
        }
    }

    // relu -> h1 hi/lo bf16 LDS: D row=(grp*4+reg), col=(nt*16+row)
#pragma unroll
    for (int g = 0; g < 4; g++) {
#pragma unroll
        for (int reg = 0; reg < 4; reg++) {
            int hrow = grp * 4 + reg;
#pragma unroll
            for (int nt = 0; nt < 4; nt++) {
                float v = fmaxf(acc[g][nt][reg], 0.f);
                __bf16 hh = (__bf16)v;
                s_hh[g][hrow * 72 + nt * 16 + row] = __builtin_bit_cast(ushort_t, hh);
                __bf16 hl = (__bf16)(v - (float)hh);
                s_hl[g][hrow * 72 + nt * 16 + row] = __builtin_bit_cast(ushort_t, hl);
            }
        }
    }
    LDS_FENCE();

    // ---- stage 2: (16x64)@(64x64) per gp; B-frags shared across 4 gps ----
    f32x4 p[4][4];
#pragma unroll
    for (int g = 0; g < 4; g++)
#pragma unroll
        for (int nt = 0; nt < 4; nt++) p[g][nt] = {0.f, 0.f, 0.f, 0.f};

#pragma unroll
    for (int ks = 0; ks < 2; ks++) {
        bf16x8 ah[4], al[4];
#pragma unroll
        for (int g = 0; g < 4; g++) {
            int ao = row * 72 + ks * 32 + grp * 8;
            ah[g] = *(const bf16x8*)&s_hh[g][ao];
            al[g] = *(const bf16x8*)&s_hl[g][ao];
        }
#pragma unroll
        for (int nt = 0; nt < 4; nt++) {
            int bo = (nt * 16 + row) * 72 + ks * 32 + grp * 8;
            bf16x8 bh = *(const bf16x8*)&w2th[bo];
            bf16x8 bl = *(const bf16x8*)&w2tl[bo];
#pragma unroll
            for (int g = 0; g < 4; g++) {
                p[g][nt] = __builtin_amdgcn_mfma_f32_16x16x32_bf16(ah[g], bh, p[g][nt], 0, 0, 0);
                p[g][nt] = __builtin_amdgcn_mfma_f32_16x16x32_bf16(al[g], bh, p[g][nt], 0, 0, 0);
                p[g][nt] = __builtin_amdgcn_mfma_f32_16x16x32_bf16(ah[g], bl, p[g][nt], 0, 0, 0);
            }
        }
    }

    // ---- relu + max over 16 rows; empty -> 0 ----
#pragma unroll
    for (int g = 0; g < 4; g++) {
        int m = m0 + g;
#pragma unroll
        for (int nt = 0; nt < 4; nt++) {
            float mv = fmaxf(fmaxf(fmaxf(p[g][nt][0], p[g][nt][1]),
                                   fmaxf(p[g][nt][2], p[g][nt][3])), 0.f);
            mv = fmaxf(mv, __shfl_xor(mv, 16));
            mv = fmaxf(mv, __shfl_xor(mv, 32));
            if (grp == 0) pooled[(size_t)m * 64 + nt * 16 + row] = empty[g] ? 0.f : mv;
        }
    }
}

// ---------------- split-K tiled fp32 GEMM: partials (BM=32, BN=32) -------
__global__ __launch_bounds__(256) void gemm_part_k(
    const float* __restrict__ A, const float* __restrict__ B,
    float* __restrict__ P, int M, int N, int Kt, int S) {
    __shared__ float As[32][33];
    __shared__ float Bs[32][33];
    int tid = threadIdx.x;
    int s = blockIdx.z;
    int klen = Kt / S;
    int k0 = s * klen;
    int m0 = blockIdx.y * 32;
    int n0 = blockIdx.x * 32;
    int tx = tid % 16, ty = tid / 16;

    float acc[2][2];
    acc[0][0] = acc[0][1] = acc[1][0] = acc[1][1] = 0.f;

    for (int kt = 0; kt < klen; kt += 32) {
        {
            int mm = tid / 8;
            int kk = (tid % 8) * 4;
            const float* ap = A + (size_t)(m0 + mm) * Kt + k0 + kt + kk;
            float4 v = *(const float4*)ap;
            As[kk + 0][mm] = v.x; As[kk + 1][mm] = v.y;
            As[kk + 2][mm] = v.z; As[kk + 3][mm] = v.w;
        }
        {
            int kk = tid / 8;
            int nn = (tid % 8) * 4;
            float4 v = *(const float4*)(B + (size_t)(k0 + kt + kk) * N + n0 + nn);
            Bs[kk][nn + 0] = v.x; Bs[kk][nn + 1] = v.y;
            Bs[kk][nn + 2] = v.z; Bs[kk][nn + 3] = v.w;
        }
        __syncthreads();
#pragma unroll
        for (int kk = 0; kk < 32; kk++) {
            float a0 = As[kk][ty * 2 + 0];
            float a1 = As[kk][ty * 2 + 1];
            float b0 = Bs[kk][tx * 2 + 0];
            float b1 = Bs[kk][tx * 2 + 1];
            acc[0][0] += a0 * b0; acc[0][1] += a0 * b1;
            acc[1][0] += a1 * b0; acc[1][1] += a1 * b1;
        }
        __syncthreads();
    }
#pragma unroll
    for (int i = 0; i < 2; i++) {
        int mrow = m0 + ty * 2 + i;
        float* pp = P + ((size_t)s * M + mrow) * N + n0 + tx * 2;
        pp[0] = acc[i][0]; pp[1] = acc[i][1];
    }
}

// ---- 3-head variant: blockIdx.z = head*S + s ----
__global__ __launch_bounds__(256) void head_gemm_k(
    const float* __restrict__ A0, const float* __restrict__ A1,
    const float* __restrict__ A2, const float* __restrict__ B0,
    const float* __restrict__ B1, const float* __restrict__ B2,
    float* __restrict__ P, int M, int N, int Kt, int S) {
    __shared__ float As[32][33];
    __shared__ float Bs[32][33];
    int tid = threadIdx.x;
    int z = blockIdx.z;
    int head = z / S, s = z % S;
    const float* A = (head == 0) ? A0 : (head == 1) ? A1 : A2;
    const float* B = (head == 0) ? B0 : (head == 1) ? B1 : B2;
    int klen = Kt / S;
    int k0 = s * klen;
    int m0 = blockIdx.y * 32;
    int n0 = blockIdx.x * 32;
    int tx = tid % 16, ty = tid / 16;

    float acc[2][2];
    acc[0][0] = acc[0][1] = acc[1][0] = acc[1][1] = 0.f;

    for (int kt = 0; kt < klen; kt += 32) {
        {
            int mm = tid / 8;
            int kk = (tid % 8) * 4;
            const float* ap = A + (size_t)(m0 + mm) * Kt + k0 + kt + kk;
            float4 v = *(const float4*)ap;
            As[kk + 0][mm] = v.x; As[kk + 1][mm] = v.y;
            As[kk + 2][mm] = v.z; As[kk + 3][mm] = v.w;
        }
        {
            int kk = tid / 8;
            int nn = (tid % 8) * 4;
            float4 v = *(const float4*)(B + (size_t)(k0 + kt + kk) * N + n0 + nn);
            Bs[kk][nn + 0] = v.x; Bs[kk][nn + 1] = v.y;
            Bs[kk][nn + 2] = v.z; Bs[kk][nn + 3] = v.w;
        }
        __syncthreads();
#pragma unroll
        for (int kk = 0; kk < 32; kk++) {
            float a0 = As[kk][ty * 2 + 0];
            float a1 = As[kk][ty * 2 + 1];
            float b0 = Bs[kk][tx * 2 + 0];
            float b1 = Bs[kk][tx * 2 + 1];
            acc[0][0] += a0 * b0; acc[0][1] += a0 * b1;
            acc[1][0] += a1 * b0; acc[1][1] += a1 * b1;
        }
        __syncthreads();
    }
#pragma unroll
    for (int i = 0; i < 2; i++) {
        int mrow = m0 + ty * 2 + i;
        float* pp = P + ((size_t)(head * S + s) * M + mrow) * N + n0 + tx * 2;
        pp[0] = acc[i][0]; pp[1] = acc[i][1];
    }
}

__global__ __launch_bounds__(256) void reduce_relu_k(const float* __restrict__ P,
                                                     float* __restrict__ C,
                                                     int MN, int S, int doRelu) {
    int i = blockIdx.x * 256 + threadIdx.x;
    if (i >= MN) return;
    float v = 0.f;
    for (int s = 0; s < S; s++) v += P[(size_t)s * MN + i];
    C[i] = doRelu ? fmaxf(v, 0.f) : v;
}

__global__ __launch_bounds__(256) void heads_reduce_k(const float* __restrict__ P,
                                                      float* __restrict__ C,
                                                      int MNper, int S) {
    int i = blockIdx.x * 256 + threadIdx.x;
    if (i >= 3 * MNper) return;
    int head = i / MNper, j = i % MNper;
    float v = 0.f;
    for (int s = 0; s < S; s++) v += P[((size_t)(head * S + s)) * MNper + j];
    C[i] = fmaxf(v, 0.f);
}

// ---------------- final head projections (merged) ----------------
__global__ __launch_bounds__(256) void head_out3_k(
    const float* __restrict__ h2s, const float* __restrict__ w_c3,
    const float* __restrict__ w_i3, const float* __restrict__ w_r3,
    const float* __restrict__ b_c3, const float* __restrict__ b_i3,
    const float* __restrict__ b_r3, float* __restrict__ out) {
    int t = blockIdx.x * 256 + threadIdx.x;
    if (t >= 128 * 9) return;
    int r = t / 9, col = t % 9;
    int head = (col == 0) ? 0 : (col == 1) ? 1 : 2;
    int p = (col < 2) ? 0 : col - 2;
    int Pn = (head == 2) ? 7 : 1;
    const float* h2 = h2s + (size_t)head * (128 * 512) + (size_t)r * 512;
    const float* w3 = (head == 0) ? w_c3 : (head == 1) ? w_i3 : w_r3;
    float acc = ((head == 0) ? b_c3 : (head == 1) ? b_i3 : b_r3)[p];
    for (int j = 0; j < 512; j++) acc += h2[j] * w3[j * Pn + p];
    out[r * 9 + col] = acc;
}

static void launch_gemm(const float* A, const float* B, float* part, float* C,
                        int M, int N, int K, hipStream_t stream) {
    const int S = 4;
    dim3 grid(N / 32, M / 32, S);
    hipLaunchKernelGGL(gemm_part_k, grid, dim3(256), 0, stream, A, B, part, M, N, K, S);
    int MN = M * N;
    hipLaunchKernelGGL(reduce_relu_k, dim3((MN + 255) / 256), dim3(256), 0, stream,
                       part, C, MN, S, 1);
}

extern "C" void kernel_launch(void* const* d_in, const int* in_sizes, int n_in,
                              void* d_out, int out_size, void* d_ws, size_t ws_size,
                              hipStream_t stream) {
    const float* xyz   = (const float*)d_in[0];
    const float* feats = (const float*)d_in[1];
    const float* rois  = (const float*)d_in[2];
    const float* w_m1  = (const float*)d_in[3];
    const float* w_m2  = (const float*)d_in[4];
    const float* w_s1  = (const float*)d_in[5];
    const float* w_s2  = (const float*)d_in[6];
    const float* w_c1  = (const float*)d_in[7];
    const float* w_c2  = (const float*)d_in[8];
    const float* w_c3  = (const float*)d_in[9];
    const float* b_c3  = (const float*)d_in[10];
    const float* w_i1  = (const float*)d_in[11];
    const float* w_i2  = (const float*)d_in[12];
    const float* w_i3  = (const float*)d_in[13];
    const float* b_i3  = (const float*)d_in[14];
    const float* w_r1  = (const float*)d_in[15];
    const float* w_r2  = (const float*)d_in[16];
    const float* w_r3  = (const float*)d_in[17];
    const float* b_r3  = (const float*)d_in[18];
    float* out = (float*)d_out;

    char* ws = (char*)d_ws;
    float*    gp     = (float*)(ws + OFF_GP);
    float*    pooled = (float*)(ws + OFF_POOLED);   // == flat (128 x 13824)
    float*    part   = (float*)(ws + OFF_PART);
    int*      cand   = (int*)(ws + OFF_CAND);       // overlaps part (pool phase only)
    int*      ncand  = (int*)(ws + OFF_NCAND);
    ushort_t* w1th   = (ushort_t*)(ws + OFF_W1TH);
    ushort_t* w1tl   = (ushort_t*)(ws + OFF_W1TL);
    ushort_t* w2th   = (ushort_t*)(ws + OFF_W2TH);
    ushort_t* w2tl   = (ushort_t*)(ws + OFF_W2TL);
    ushort_t* fhi    = (ushort_t*)(ws + OFF_FHI);   // overlaps T1/SFC (pool phase only)
    ushort_t* flo    = (ushort_t*)(ws + OFF_FLO);
    float*    t1     = (float*)(ws + OFF_T1);
    float*    sfc    = (float*)(ws + OFF_SFC);
    float*    h1s    = (float*)(ws + OFF_H1S);
    float*    h2s    = (float*)(ws + OFF_H2S);

    hipLaunchKernelGGL(grid_points_k, dim3((M_GP + 255) / 256), dim3(256), 0, stream,
                       rois, gp);
    hipLaunchKernelGGL(prep_w_k, dim3(42), dim3(256), 0, stream,
                       w_m1, w_m2, w1th, w1tl, w2th, w2tl);
    hipLaunchKernelGGL(prep_feats_k, dim3(2048), dim3(256), 0, stream, feats, fhi, flo);
    hipLaunchKernelGGL(roi_cand_k, dim3(R_ROIS), dim3(64), 0, stream, rois, xyz, cand, ncand);
    hipLaunchKernelGGL(grid_pool_mfma4_k, dim3(M_GP / 4), dim3(64), 0, stream,
                       xyz, fhi, flo, gp, cand, ncand, w1th, w1tl, w2th, w2tl, pooled);

    // shared FC (fp32)
    launch_gemm(pooled, w_s1, part, t1, 128, 1024, 13824, stream);
    launch_gemm(t1, w_s2, part, sfc, 128, 512, 1024, stream);

    // heads layer 1 (merged): sfc @ {w_c1,w_i1,w_r1} -> h1s
    {
        const int S = 2;
        dim3 grid(1024 / 32, 128 / 32, 3 * S);
        hipLaunchKernelGGL(head_gemm_k, grid, dim3(256), 0, stream,
                           sfc, sfc, sfc, w_c1, w_i1, w_r1, part, 128, 1024, 512, S);
        int MNper = 128 * 1024;
        hipLaunchKernelGGL(heads_reduce_k, dim3((3 * MNper + 255) / 256), dim3(256), 0,
                           stream, part, h1s, MNper, S);
    }
    // heads layer 2 (merged): h1s @ {w_c2,w_i2,w_r2} -> h2s
    {
        const int S = 2;
        dim3 grid(512 / 32, 128 / 32, 3 * S);
        hipLaunchKernelGGL(head_gemm_k, grid, dim3(256), 0, stream,
                           h1s, h1s + 131072, h1s + 262144, w_c2, w_i2, w_r2,
                           part, 128, 512, 1024, S);
        int MNper = 128 * 512;
        hipLaunchKernelGGL(heads_reduce_k, dim3((3 * MNper + 255) / 256), dim3(256), 0,
                           stream, part, h2s, MNper, S);
    }
    // final projections (merged)
    hipLaunchKernelGGL(head_out3_k, dim3((128 * 9 + 255) / 256), dim3(256), 0, stream,
                       h2s, w_c3, w_i3, w_r3, b_c3, b_i3, b_r3, out);
}

// Round 6
// 290.281 us; speedup vs baseline: 2.4484x; 1.2878x over previous
//
#include <hip/hip_runtime.h>

typedef float  f32x4  __attribute__((ext_vector_type(4)));
typedef __bf16 bf16x8 __attribute__((ext_vector_type(8)));
typedef unsigned short ushort_t;

#define N_PTS 4096
#define R_ROIS 128
#define M_GP  27648
#define LDS_FENCE() asm volatile("s_waitcnt lgkmcnt(0)" ::: "memory")

// ---------------- workspace layout (bytes), total 13,763,072 ----------------
static constexpr size_t OFF_GP     = 0;          // 331776
static constexpr size_t OFF_POOLED = 331776;     // 27648*64*4 = 7077888 (== flat 128x13824)
// pooled region is dead after the s1 GEMM; h1s/h2s reuse it:
static constexpr size_t OFF_H1S    = OFF_POOLED;             // 3*128*1024*4 = 1572864
static constexpr size_t OFF_H2S    = OFF_POOLED + 1572864;   // 3*128*512*4 = 786432
static constexpr size_t OFF_PART   = 7409664;    // 4 MB partials (s1 S=8); cand overlaps
static constexpr size_t OFF_CAND   = OFF_PART;   // 128*4096*4 = 2097152 (pool phase)
static constexpr size_t OFF_NCAND  = 11603968;   // 512
static constexpr size_t OFF_W1TH   = 11604480;   // 10752*2
static constexpr size_t OFF_W1TL   = 11625984;   // 10752*2
static constexpr size_t OFF_W2TH   = 11647488;   // 4608*2
static constexpr size_t OFF_W2TL   = 11656704;   // 4608*2 (end 11665920)
// pool phase only (overlap t1/sfc which are FC-phase):
static constexpr size_t OFF_FHI    = 11665920;   // 1048576
static constexpr size_t OFF_FLO    = 12714496;   // 1048576 (end 13763072)
static constexpr size_t OFF_T1     = 11665920;   // 524288  (FC phase)
static constexpr size_t OFF_SFC    = 12190208;   // 262144  (FC phase, end 12452352)

static __device__ inline ushort_t f2bf(float f) {
    unsigned int u = __float_as_uint(f);
    unsigned int r = u + 0x7FFFu + ((u >> 16) & 1u);
    return (ushort_t)(r >> 16);
}
static __device__ inline float bf2f(ushort_t h) {
    return __uint_as_float(((unsigned int)h) << 16);
}

// ---------------- grid points ----------------
__global__ __launch_bounds__(256) void grid_points_k(const float* __restrict__ rois,
                                                     float* __restrict__ gp) {
    int m = blockIdx.x * 256 + threadIdx.x;
    if (m >= M_GP) return;
    int r = m / 216, t = m % 216;
    int gi = t / 36, gj = (t / 6) % 6, gk = t % 6;
    const float* roi = rois + r * 7;
    float sx = roi[3], sy = roi[4], sz = roi[5];
    float lx = ((float)gi + 0.5f) / 6.0f * sx - sx * 0.5f;
    float ly = ((float)gj + 0.5f) / 6.0f * sy - sy * 0.5f;
    float lz = ((float)gk + 0.5f) / 6.0f * sz - sz * 0.5f;
    float c = cosf(roi[6]), s = sinf(roi[6]);
    gp[m * 3 + 0] = lx * c - ly * s + roi[0];
    gp[m * 3 + 1] = lx * s + ly * c + roi[1];
    gp[m * 3 + 2] = lz + roi[2];
}

// ---------------- feats -> hi/lo bf16 ----------------
__global__ __launch_bounds__(256) void prep_feats_k(const float* __restrict__ feats,
                                                    ushort_t* __restrict__ fhi,
                                                    ushort_t* __restrict__ flo) {
    int i = blockIdx.x * 256 + threadIdx.x;
    if (i >= N_PTS * 128) return;
    float v = feats[i];
    __bf16 h = (__bf16)v;
    fhi[i] = __builtin_bit_cast(ushort_t, h);
    __bf16 l = (__bf16)(v - (float)h);
    flo[i] = __builtin_bit_cast(ushort_t, l);
}

// ---------------- weight prep: PERMUTED transpose + pad + hi/lo bf16 ----
__global__ __launch_bounds__(256) void prep_w_k(const float* __restrict__ w1,
                                                const float* __restrict__ w2,
                                                ushort_t* __restrict__ w1th,
                                                ushort_t* __restrict__ w1tl,
                                                ushort_t* __restrict__ w2th,
                                                ushort_t* __restrict__ w2tl) {
    int t = blockIdx.x * 256 + threadIdx.x;
    if (t < 10752) {
        int col = t / 168, p = t % 168;
        float v = (p < 128) ? w1[(3 + p) * 64 + col]
                : (p < 131) ? w1[(p - 128) * 64 + col] : 0.f;
        ushort_t hi = f2bf(v);
        w1th[t] = hi;
        w1tl[t] = f2bf(v - bf2f(hi));
    }
    if (t < 4608) {
        int col = t / 72, k = t % 72;
        float v = (k < 64) ? w2[k * 64 + col] : 0.f;
        ushort_t hi = f2bf(v);
        w2th[t] = hi;
        w2tl[t] = f2bf(v - bf2f(hi));
    }
}

// ---------------- per-RoI candidate lists ----------------
__global__ __launch_bounds__(64) void roi_cand_k(const float* __restrict__ rois,
                                                 const float* __restrict__ xyz,
                                                 int* __restrict__ cand,
                                                 int* __restrict__ ncand) {
    int r = blockIdx.x;
    int lane = threadIdx.x;
    const float* roi = rois + r * 7;
    float cx = roi[0], cy = roi[1], cz = roi[2];
    float sx = roi[3], sy = roi[4], sz = roi[5];
    float Rc = 0.8f + 0.4166667f * sqrtf(sx * sx + sy * sy + sz * sz) + 0.01f;
    float Rc2 = Rc * Rc;
    int* cl = cand + r * N_PTS;
    int cnt = 0;
    for (int base = 0; base < N_PTS; base += 64) {
        int i = base + lane;
        float dx = xyz[i * 3 + 0] - cx;
        float dy = xyz[i * 3 + 1] - cy;
        float dz = xyz[i * 3 + 2] - cz;
        bool in = dx * dx + dy * dy + dz * dz < Rc2;
        unsigned long long ball = __ballot(in);
        int before = __popcll(ball & ((1ull << lane) - 1ull));
        if (in) cl[cnt + before] = i;
        cnt += __popcll(ball);
    }
    if (lane == 0) ncand[r] = cnt;
}

// ---------------- search + split-bf16 MFMA point-MLP + maxpool ----------
__global__ __launch_bounds__(64) void grid_pool_mfma4_k(
    const float* __restrict__ xyz,
    const ushort_t* __restrict__ fhi, const ushort_t* __restrict__ flo,
    const float* __restrict__ gp, const int* __restrict__ cand,
    const int* __restrict__ ncand,
    const ushort_t* __restrict__ w1th, const ushort_t* __restrict__ w1tl,
    const ushort_t* __restrict__ w2th, const ushort_t* __restrict__ w2tl,
    float* __restrict__ pooled) {
    __shared__ __attribute__((aligned(16))) ushort_t s_hh[4][1152];  // [16][72]
    __shared__ __attribute__((aligned(16))) ushort_t s_hl[4][1152];
    __shared__ int s_idx[4][16];

    int lane = threadIdx.x;
    const float R2 = (float)(0.8 * 0.8);
    int row = lane & 15, grp = lane >> 4;
    int m0 = blockIdx.x * 4;

    bool empty[4];
    float gxv[4], gyv[4], gzv[4];

#pragma unroll
    for (int g = 0; g < 4; g++) {
        int m = m0 + g;
        int r = m / 216;
        float gx = gp[m * 3 + 0], gy = gp[m * 3 + 1], gz = gp[m * 3 + 2];
        gxv[g] = gx; gyv[g] = gy; gzv[g] = gz;
        int nc = ncand[r];
        const int* cl = cand + (size_t)r * N_PTS;
        int count = 0;
        for (int base = 0; base < nc; base += 64) {
            int t = base + lane;
            bool in = false;
            int i = 0;
            if (t < nc) {
                i = cl[t];
                float dx = xyz[i * 3 + 0] - gx;
                float dy = xyz[i * 3 + 1] - gy;
                float dz = xyz[i * 3 + 2] - gz;
                in = dx * dx + dy * dy + dz * dz < R2;
            }
            unsigned long long ball = __ballot(in);
            int before = __popcll(ball & ((1ull << lane) - 1ull));
            int pos = count + before;
            if (in && pos < 16) s_idx[g][pos] = i;
            count += __popcll(ball);
            if (count >= 16) break;
        }
        int c = min(count, 16);
        empty[g] = (c == 0);
        if (lane == 0) {
            if (c == 0) {
                for (int p = 0; p < 16; p++) s_idx[g][p] = 0;
            } else {
                LDS_FENCE();
                int f = s_idx[g][0];
                for (int p = c; p < 16; p++) s_idx[g][p] = f;
            }
        }
    }
    LDS_FENCE();

    int pi[4];
    float rx[4], ry[4], rz[4];
#pragma unroll
    for (int g = 0; g < 4; g++) {
        pi[g] = s_idx[g][row];
        rx[g] = xyz[pi[g] * 3 + 0] - gxv[g];
        ry[g] = xyz[pi[g] * 3 + 1] - gyv[g];
        rz[g] = xyz[pi[g] * 3 + 2] - gzv[g];
    }

    f32x4 acc[4][4];
#pragma unroll
    for (int g = 0; g < 4; g++)
#pragma unroll
        for (int nt = 0; nt < 4; nt++) acc[g][nt] = {0.f, 0.f, 0.f, 0.f};

#pragma unroll
    for (int ks = 0; ks < 4; ks++) {
        bf16x8 ah[4], al[4];
#pragma unroll
        for (int g = 0; g < 4; g++) {
            size_t fo = (size_t)pi[g] * 128 + ks * 32 + grp * 8;
            ah[g] = *(const bf16x8*)&fhi[fo];
            al[g] = *(const bf16x8*)&flo[fo];
        }
#pragma unroll
        for (int nt = 0; nt < 4; nt++) {
            int bo = (nt * 16 + row) * 168 + ks * 32 + grp * 8;
            bf16x8 bh = *(const bf16x8*)&w1th[bo];
            bf16x8 bl = *(const bf16x8*)&w1tl[bo];
#pragma unroll
            for (int g = 0; g < 4; g++) {
                acc[g][nt] = __builtin_amdgcn_mfma_f32_16x16x32_bf16(ah[g], bh, acc[g][nt], 0, 0, 0);
                acc[g][nt] = __builtin_amdgcn_mfma_f32_16x16x32_bf16(al[g], bh, acc[g][nt], 0, 0, 0);
                acc[g][nt] = __builtin_amdgcn_mfma_f32_16x16x32_bf16(ah[g], bl, acc[g][nt], 0, 0, 0);
            }
        }
    }
    {
        bf16x8 ah[4], al[4];
#pragma unroll
        for (int g = 0; g < 4; g++) {
            bf16x8 zh = {};
            bf16x8 zl = {};
            if (grp == 0) {
                __bf16 h0 = (__bf16)rx[g], h1 = (__bf16)ry[g], h2 = (__bf16)rz[g];
                zh[0] = h0; zl[0] = (__bf16)(rx[g] - (float)h0);
                zh[1] = h1; zl[1] = (__bf16)(ry[g] - (float)h1);
                zh[2] = h2; zl[2] = (__bf16)(rz[g] - (float)h2);
            }
            ah[g] = zh; al[g] = zl;
        }
#pragma unroll
        for (int nt = 0; nt < 4; nt++) {
            int bo = (nt * 16 + row) * 168 + 128 + grp * 8;
            bf16x8 bh = *(const bf16x8*)&w1th[bo];
            bf16x8 bl = *(const bf16x8*)&w1tl[bo];
#pragma unroll
            for (int g = 0; g < 4; g++) {
                acc[g][nt] = __builtin_amdgcn_mfma_f32_16x16x32_bf16(ah[g], bh, acc[g][nt], 0, 0, 0);
                acc[g][nt] = __builtin_amdgcn_mfma_f32_16x16x32_bf16(al[g], bh, acc[g][nt], 0, 0, 0);
                acc[g][nt] = __builtin_amdgcn_mfma_f32_16x16x32_bf16(ah[g], bl, acc[g][nt], 0, 0, 0);
            }
        }
    }

#pragma unroll
    for (int g = 0; g < 4; g++) {
#pragma unroll
        for (int reg = 0; reg < 4; reg++) {
            int hrow = grp * 4 + reg;
#pragma unroll
            for (int nt = 0; nt < 4; nt++) {
                float v = fmaxf(acc[g][nt][reg], 0.f);
                __bf16 hh = (__bf16)v;
                s_hh[g][hrow * 72 + nt * 16 + row] = __builtin_bit_cast(ushort_t, hh);
                __bf16 hl = (__bf16)(v - (float)hh);
                s_hl[g][hrow * 72 + nt * 16 + row] = __builtin_bit_cast(ushort_t, hl);
            }
        }
    }
    LDS_FENCE();

    f32x4 p[4][4];
#pragma unroll
    for (int g = 0; g < 4; g++)
#pragma unroll
        for (int nt = 0; nt < 4; nt++) p[g][nt] = {0.f, 0.f, 0.f, 0.f};

#pragma unroll
    for (int ks = 0; ks < 2; ks++) {
        bf16x8 ah[4], al[4];
#pragma unroll
        for (int g = 0; g < 4; g++) {
            int ao = row * 72 + ks * 32 + grp * 8;
            ah[g] = *(const bf16x8*)&s_hh[g][ao];
            al[g] = *(const bf16x8*)&s_hl[g][ao];
        }
#pragma unroll
        for (int nt = 0; nt < 4; nt++) {
            int bo = (nt * 16 + row) * 72 + ks * 32 + grp * 8;
            bf16x8 bh = *(const bf16x8*)&w2th[bo];
            bf16x8 bl = *(const bf16x8*)&w2tl[bo];
#pragma unroll
            for (int g = 0; g < 4; g++) {
                p[g][nt] = __builtin_amdgcn_mfma_f32_16x16x32_bf16(ah[g], bh, p[g][nt], 0, 0, 0);
                p[g][nt] = __builtin_amdgcn_mfma_f32_16x16x32_bf16(al[g], bh, p[g][nt], 0, 0, 0);
                p[g][nt] = __builtin_amdgcn_mfma_f32_16x16x32_bf16(ah[g], bl, p[g][nt], 0, 0, 0);
            }
        }
    }

#pragma unroll
    for (int g = 0; g < 4; g++) {
        int m = m0 + g;
#pragma unroll
        for (int nt = 0; nt < 4; nt++) {
            float mv = fmaxf(fmaxf(fmaxf(p[g][nt][0], p[g][nt][1]),
                                   fmaxf(p[g][nt][2], p[g][nt][3])), 0.f);
            mv = fmaxf(mv, __shfl_xor(mv, 16));
            mv = fmaxf(mv, __shfl_xor(mv, 32));
            if (grp == 0) pooled[(size_t)m * 64 + nt * 16 + row] = empty[g] ? 0.f : mv;
        }
    }
}

// ======== split-bf16 MFMA GEMM core: BM=128, BN=64, BK=32, 256 threads =====
// A fp32 [128][Kt] row-major, B fp32 [Kt][N] row-major. Partials to P.
// Hi/lo conversion happens during LDS staging. Fragment layout identical to
// the HW-verified grid_pool kernel (A=[m][k], B=[n][k], D col=lane&15).
__device__ inline void mfma_gemm_core(const float* __restrict__ A,
                                      const float* __restrict__ B,
                                      float* __restrict__ P, size_t p_base,
                                      int N, int Kt, int k0, int klen, int n0) {
    __shared__ __attribute__((aligned(16))) ushort_t As_h[128][40];
    __shared__ __attribute__((aligned(16))) ushort_t As_l[128][40];
    __shared__ __attribute__((aligned(16))) ushort_t Bs_h[64][40];
    __shared__ __attribute__((aligned(16))) ushort_t Bs_l[64][40];

    int tid = threadIdx.x;
    int w = tid >> 6, lane = tid & 63;
    int row = lane & 15, grp = lane >> 4;

    f32x4 acc[2][4];
#pragma unroll
    for (int mi = 0; mi < 2; mi++)
#pragma unroll
        for (int ni = 0; ni < 4; ni++) acc[mi][ni] = {0.f, 0.f, 0.f, 0.f};

    for (int kt = 0; kt < klen; kt += 32) {
        {   // stage A: 128 rows x 32 k, convert to hi/lo
            int r0 = tid >> 3;           // 0..31
            int kk = (tid & 7) * 4;      // 0..28
#pragma unroll
            for (int i = 0; i < 4; i++) {
                int mrow = r0 + i * 32;
                float4 v = *(const float4*)(A + (size_t)mrow * Kt + k0 + kt + kk);
                float vv[4] = {v.x, v.y, v.z, v.w};
#pragma unroll
                for (int j = 0; j < 4; j++) {
                    __bf16 h = (__bf16)vv[j];
                    As_h[mrow][kk + j] = __builtin_bit_cast(ushort_t, h);
                    __bf16 l = (__bf16)(vv[j] - (float)h);
                    As_l[mrow][kk + j] = __builtin_bit_cast(ushort_t, l);
                }
            }
        }
        {   // stage B transposed: Bs[n][k] from B[k][n]
            int kr = tid >> 4;           // 0..15
            int nn = (tid & 15) * 4;     // 0..60
#pragma unroll
            for (int i = 0; i < 2; i++) {
                int krow = kr + i * 16;
                float4 v = *(const float4*)(B + (size_t)(k0 + kt + krow) * N + n0 + nn);
                float vv[4] = {v.x, v.y, v.z, v.w};
#pragma unroll
                for (int j = 0; j < 4; j++) {
                    __bf16 h = (__bf16)vv[j];
                    Bs_h[nn + j][krow] = __builtin_bit_cast(ushort_t, h);
                    __bf16 l = (__bf16)(vv[j] - (float)h);
                    Bs_l[nn + j][krow] = __builtin_bit_cast(ushort_t, l);
                }
            }
        }
        __syncthreads();
#pragma unroll
        for (int mi = 0; mi < 2; mi++) {
            int arow = (w * 2 + mi) * 16 + row;
            bf16x8 ah = *(const bf16x8*)&As_h[arow][grp * 8];
            bf16x8 al = *(const bf16x8*)&As_l[arow][grp * 8];
#pragma unroll
            for (int ni = 0; ni < 4; ni++) {
                bf16x8 bh = *(const bf16x8*)&Bs_h[ni * 16 + row][grp * 8];
                bf16x8 bl = *(const bf16x8*)&Bs_l[ni * 16 + row][grp * 8];
                acc[mi][ni] = __builtin_amdgcn_mfma_f32_16x16x32_bf16(ah, bh, acc[mi][ni], 0, 0, 0);
                acc[mi][ni] = __builtin_amdgcn_mfma_f32_16x16x32_bf16(al, bh, acc[mi][ni], 0, 0, 0);
                acc[mi][ni] = __builtin_amdgcn_mfma_f32_16x16x32_bf16(ah, bl, acc[mi][ni], 0, 0, 0);
            }
        }
        __syncthreads();
    }
    // write partials: D element (mi,ni,reg): m = frag*16 + grp*4+reg, n = ni*16+row
#pragma unroll
    for (int mi = 0; mi < 2; mi++) {
#pragma unroll
        for (int ni = 0; ni < 4; ni++) {
#pragma unroll
            for (int reg = 0; reg < 4; reg++) {
                int mrow = (w * 2 + mi) * 16 + grp * 4 + reg;
                int ncol = n0 + ni * 16 + row;
                P[p_base + (size_t)mrow * N + ncol] = acc[mi][ni][reg];
            }
        }
    }
}

// single-matrix split-K: grid (N/64, 1, S)
__global__ __launch_bounds__(256) void mfma_gemm_k(
    const float* __restrict__ A, const float* __restrict__ B,
    float* __restrict__ P, int N, int Kt, int S) {
    int s = blockIdx.z;
    int klen = Kt / S;
    mfma_gemm_core(A, B, P, (size_t)s * 128 * N, N, Kt, s * klen, klen,
                   blockIdx.x * 64);
}

// 3-head variant: grid (N/64, 1, 3*S); A stride selects head
__global__ __launch_bounds__(256) void mfma_head_gemm_k(
    const float* __restrict__ A0, size_t a_stride,
    const float* __restrict__ B0, const float* __restrict__ B1,
    const float* __restrict__ B2,
    float* __restrict__ P, int N, int Kt, int S) {
    int z = blockIdx.z;
    int head = z / S, s = z % S;
    const float* A = A0 + (size_t)head * a_stride;
    const float* B = (head == 0) ? B0 : (head == 1) ? B1 : B2;
    int klen = Kt / S;
    mfma_gemm_core(A, B, P, (size_t)z * 128 * N, N, Kt, s * klen, klen,
                   blockIdx.x * 64);
}

__global__ __launch_bounds__(256) void reduce_relu_k(const float* __restrict__ P,
                                                     float* __restrict__ C,
                                                     int MN, int S) {
    int i = blockIdx.x * 256 + threadIdx.x;
    if (i >= MN) return;
    float v = 0.f;
    for (int s = 0; s < S; s++) v += P[(size_t)s * MN + i];
    C[i] = fmaxf(v, 0.f);
}

__global__ __launch_bounds__(256) void heads_reduce_k(const float* __restrict__ P,
                                                      float* __restrict__ C,
                                                      int MNper, int S) {
    int i = blockIdx.x * 256 + threadIdx.x;
    if (i >= 3 * MNper) return;
    int head = i / MNper, j = i % MNper;
    float v = 0.f;
    for (int s = 0; s < S; s++) v += P[((size_t)(head * S + s)) * MNper + j];
    C[i] = fmaxf(v, 0.f);
}

// ---------------- final head projections (merged) ----------------
__global__ __launch_bounds__(256) void head_out3_k(
    const float* __restrict__ h2s, const float* __restrict__ w_c3,
    const float* __restrict__ w_i3, const float* __restrict__ w_r3,
    const float* __restrict__ b_c3, const float* __restrict__ b_i3,
    const float* __restrict__ b_r3, float* __restrict__ out) {
    int t = blockIdx.x * 256 + threadIdx.x;
    if (t >= 128 * 9) return;
    int r = t / 9, col = t % 9;
    int head = (col == 0) ? 0 : (col == 1) ? 1 : 2;
    int p = (col < 2) ? 0 : col - 2;
    int Pn = (head == 2) ? 7 : 1;
    const float* h2 = h2s + (size_t)head * (128 * 512) + (size_t)r * 512;
    const float* w3 = (head == 0) ? w_c3 : (head == 1) ? w_i3 : w_r3;
    float acc = ((head == 0) ? b_c3 : (head == 1) ? b_i3 : b_r3)[p];
    for (int j = 0; j < 512; j++) acc += h2[j] * w3[j * Pn + p];
    out[r * 9 + col] = acc;
}

extern "C" void kernel_launch(void* const* d_in, const int* in_sizes, int n_in,
                              void* d_out, int out_size, void* d_ws, size_t ws_size,
                              hipStream_t stream) {
    const float* xyz   = (const float*)d_in[0];
    const float* feats = (const float*)d_in[1];
    const float* rois  = (const float*)d_in[2];
    const float* w_m1  = (const float*)d_in[3];
    const float* w_m2  = (const float*)d_in[4];
    const float* w_s1  = (const float*)d_in[5];
    const float* w_s2  = (const float*)d_in[6];
    const float* w_c1  = (const float*)d_in[7];
    const float* w_c2  = (const float*)d_in[8];
    const float* w_c3  = (const float*)d_in[9];
    const float* b_c3  = (const float*)d_in[10];
    const float* w_i1  = (const float*)d_in[11];
    const float* w_i2  = (const float*)d_in[12];
    const float* w_i3  = (const float*)d_in[13];
    const float* b_i3  = (const float*)d_in[14];
    const float* w_r1  = (const float*)d_in[15];
    const float* w_r2  = (const float*)d_in[16];
    const float* w_r3  = (const float*)d_in[17];
    const float* b_r3  = (const float*)d_in[18];
    float* out = (float*)d_out;

    char* ws = (char*)d_ws;
    float*    gp     = (float*)(ws + OFF_GP);
    float*    pooled = (float*)(ws + OFF_POOLED);
    float*    part   = (float*)(ws + OFF_PART);
    int*      cand   = (int*)(ws + OFF_CAND);
    int*      ncand  = (int*)(ws + OFF_NCAND);
    ushort_t* w1th   = (ushort_t*)(ws + OFF_W1TH);
    ushort_t* w1tl   = (ushort_t*)(ws + OFF_W1TL);
    ushort_t* w2th   = (ushort_t*)(ws + OFF_W2TH);
    ushort_t* w2tl   = (ushort_t*)(ws + OFF_W2TL);
    ushort_t* fhi    = (ushort_t*)(ws + OFF_FHI);
    ushort_t* flo    = (ushort_t*)(ws + OFF_FLO);
    float*    t1     = (float*)(ws + OFF_T1);
    float*    sfc    = (float*)(ws + OFF_SFC);
    float*    h1s    = (float*)(ws + OFF_H1S);
    float*    h2s    = (float*)(ws + OFF_H2S);

    hipLaunchKernelGGL(grid_points_k, dim3((M_GP + 255) / 256), dim3(256), 0, stream,
                       rois, gp);
    hipLaunchKernelGGL(prep_w_k, dim3(42), dim3(256), 0, stream,
                       w_m1, w_m2, w1th, w1tl, w2th, w2tl);
    hipLaunchKernelGGL(prep_feats_k, dim3(2048), dim3(256), 0, stream, feats, fhi, flo);
    hipLaunchKernelGGL(roi_cand_k, dim3(R_ROIS), dim3(64), 0, stream, rois, xyz, cand, ncand);
    hipLaunchKernelGGL(grid_pool_mfma4_k, dim3(M_GP / 4), dim3(64), 0, stream,
                       xyz, fhi, flo, gp, cand, ncand, w1th, w1tl, w2th, w2tl, pooled);

    // s1: flat(128x13824) @ w_s1 -> t1 (relu), split-K S=8, 128 blocks
    hipLaunchKernelGGL(mfma_gemm_k, dim3(16, 1, 8), dim3(256), 0, stream,
                       pooled, w_s1, part, 1024, 13824, 8);
    hipLaunchKernelGGL(reduce_relu_k, dim3((128 * 1024 + 255) / 256), dim3(256), 0,
                       stream, part, t1, 128 * 1024, 8);

    // s2: t1 @ w_s2 -> sfc (relu), S=4
    hipLaunchKernelGGL(mfma_gemm_k, dim3(8, 1, 4), dim3(256), 0, stream,
                       t1, w_s2, part, 512, 1024, 4);
    hipLaunchKernelGGL(reduce_relu_k, dim3((128 * 512 + 255) / 256), dim3(256), 0,
                       stream, part, sfc, 128 * 512, 4);

    // heads layer 1: sfc @ {w_c1,w_i1,w_r1} -> h1s, S=2
    hipLaunchKernelGGL(mfma_head_gemm_k, dim3(16, 1, 6), dim3(256), 0, stream,
                       sfc, (size_t)0, w_c1, w_i1, w_r1, part, 1024, 512, 2);
    hipLaunchKernelGGL(heads_reduce_k, dim3((3 * 128 * 1024 + 255) / 256), dim3(256), 0,
                       stream, part, h1s, 128 * 1024, 2);

    // heads layer 2: h1s @ {w_c2,w_i2,w_r2} -> h2s, S=2
    hipLaunchKernelGGL(mfma_head_gemm_k, dim3(8, 1, 6), dim3(256), 0, stream,
                       h1s, (size_t)(128 * 1024), w_c2, w_i2, w_r2, part, 512, 1024, 2);
    hipLaunchKernelGGL(heads_reduce_k, dim3((3 * 128 * 512 + 255) / 256), dim3(256), 0,
                       stream, part, h2s, 128 * 512, 2);

    // final projections (merged)
    hipLaunchKernelGGL(head_out3_k, dim3((128 * 9 + 255) / 256), dim3(256), 0, stream,
                       h2s, w_c3, w_i3, w_r3, b_c3, b_i3, b_r3, out);
}